// Round 10
// baseline (450.076 us; speedup 1.0000x reference)
//
#include <hip/hip_runtime.h>

#define NF 16384
#define NB 4096
#define EF 262144
#define EB 65536
#define FBLK 1024   // EF/256
#define BBLK 256    // EB/256

typedef __attribute__((ext_vector_type(8))) short bf16x8;
typedef __attribute__((ext_vector_type(4))) float f32x4;

__device__ __forceinline__ short f2b(float f) {
  unsigned u = __float_as_uint(f);
  u += 0x7fff + ((u >> 16) & 1);   // RNE
  return (short)(u >> 16);
}
__device__ __forceinline__ unsigned pack2(float lo, float hi) {
  return (unsigned)(unsigned short)f2b(lo) | ((unsigned)(unsigned short)f2b(hi) << 16);
}
__device__ __forceinline__ float b2f_lo(unsigned u) {
  return __uint_as_float(u << 16);
}
__device__ __forceinline__ float b2f_hi(unsigned u) {
  return __uint_as_float(u & 0xffff0000u);
}

// ---------------------------------------------------------------------------
// Target CSR: histogram (merged fluid+boundary).
// ---------------------------------------------------------------------------
__global__ void __launch_bounds__(256) dual_hist(const int* __restrict__ fi,
                                                 const int* __restrict__ bfi,
                                                 int* __restrict__ fhist,
                                                 int* __restrict__ bhist) {
  int bid = blockIdx.x;
  if (bid < FBLK) {
    int e = bid * 256 + threadIdx.x;
    atomicAdd(fhist + fi[e], 1);
  } else {
    int e = (bid - FBLK) * 256 + threadIdx.x;
    atomicAdd(bhist + bfi[e], 1);
  }
}

__global__ void __launch_bounds__(1024) csr_scan2(const int* __restrict__ fhist,
                                                  const int* __restrict__ bhist,
                                                  int* __restrict__ fstart, int* __restrict__ fcur,
                                                  int* __restrict__ bstart, int* __restrict__ bcur) {
  const int* hist = blockIdx.x ? bhist : fhist;
  int* start = blockIdx.x ? bstart : fstart;
  int* cursor = blockIdx.x ? bcur : fcur;
  __shared__ int wtot[16];
  int t = threadIdx.x;
  int lane = t & 63, wv = t >> 6;
  int base = t * 16;
  int vals[16];
  int s = 0;
#pragma unroll
  for (int k = 0; k < 16; k++) { vals[k] = hist[base + k]; s += vals[k]; }
  int ss = s;
  for (int off = 1; off < 64; off <<= 1) {
    int o = __shfl_up(ss, off, 64);
    if (lane >= off) ss += o;
  }
  if (lane == 63) wtot[wv] = ss;
  __syncthreads();
  if (t < 16) {
    int v = wtot[t];
    int vv = v;
    for (int off = 1; off < 16; off <<= 1) {
      int o = __shfl_up(vv, off, 64);
      if (t >= off) vv += o;
    }
    wtot[t] = vv - v;
  }
  __syncthreads();
  int run = ss - s + wtot[wv];
#pragma unroll
  for (int k = 0; k < 16; k++) { start[base + k] = run; cursor[base + k] = run; run += vals[k]; }
  if (t == 1023) start[16384] = run;
}

// ---------------------------------------------------------------------------
// Merged scatter + payload + tent-basis: per edge, compute cell/weights and
// write packed payload directly at its CSR position (one pass, no edge ids).
// ---------------------------------------------------------------------------
__global__ void __launch_bounds__(256) dual_scatter_payload(
    const int* __restrict__ fi, const int* __restrict__ fj,
    const int* __restrict__ bfi, const int* __restrict__ bb,
    const float* __restrict__ fp, const float* __restrict__ bp,
    const float* __restrict__ supportp,
    int* __restrict__ fcur, int* __restrict__ bcur,
    unsigned* __restrict__ fpk, float4* __restrict__ fwt,
    unsigned* __restrict__ bpk, float4* __restrict__ bwt) {
  int bid = blockIdx.x;
  bool fluid = bid < FBLK;
  int e = (fluid ? bid : bid - FBLK) * 256 + threadIdx.x;
  int ti = fluid ? fi[e] : bfi[e];
  int si = fluid ? fj[e] : bb[e];
  const float2* pT2 = (const float2*)fp;
  const float2* pS2 = fluid ? (const float2*)fp : (const float2*)bp;
  float sign = fluid ? -1.f : 1.f;
  float inv_sup = 1.0f / supportp[0];
  float2 pt = pT2[ti];
  float2 ps = pS2[si];
  // d = sign*(src-tgt)/support. (-1)*(+0) = -0 preserves reference signed
  // zeros for self-edges (atan2(-0,-0) = -pi).
  float dx = sign * ((ps.x - pt.x) * inv_sup);
  float dy = sign * ((ps.y - pt.y) * inv_sup);
  dx = fminf(fmaxf(dx, -1.f), 1.f);
  dy = fminf(fmaxf(dy, -1.f), 1.f);
  float r = sqrtf(dx * dx + dy * dy + 1e-12f);
  float theta;
  if (dx == 0.0f && dy == 0.0f) {
    float mag = __builtin_signbitf(dx) ? 3.14159265358979323846f : 0.0f;
    theta = __builtin_signbitf(dy) ? -mag : mag;
  } else {
    theta = atan2f(dy, dx);
  }
  float u = 2.f * r - 1.f;
  float v = theta * (1.f / 3.14159265358979323846f);
  float tu = (u + 1.f) * 3.5f;
  float tv = (v + 1.f) * 3.5f;
  int iu = min(max((int)floorf(tu), 0), 6);
  int iv = min(max((int)floorf(tv), 0), 6);
  float wu0 = fmaxf(0.f, 1.f - fabsf(tu - (float)iu));
  float wu1 = fmaxf(0.f, 1.f - fabsf(tu - (float)(iu + 1)));
  float wv0 = fmaxf(0.f, 1.f - fabsf(tv - (float)iv));
  float wv1 = fmaxf(0.f, 1.f - fabsf(tv - (float)(iv + 1)));
  unsigned pk = (unsigned)si | ((unsigned)(iu * 8 + iv) << 14);
  float4 w4 = make_float4(wu0 * wv0, wu0 * wv1, wu1 * wv0, wu1 * wv1);
  if (fluid) {
    int p = atomicAdd(fcur + ti, 1);
    fpk[p] = pk; fwt[p] = w4;
  } else {
    int p = atomicAdd(bcur + ti, 1);
    bpk[p] = pk; bwt[p] = w4;
  }
}

__global__ void __launch_bounds__(256) buildBT(const float* __restrict__ W,
                                               short* __restrict__ BT, int K) {
  int tid = blockIdx.x * 256 + threadIdx.x;
  if (tid >= 4096 * K) return;
  int k = tid % K, n = tid / K;
  BT[tid] = f2b(W[((size_t)(n >> 6) * K + k) * 64 + (n & 63)]);
}

// ---------------------------------------------------------------------------
// Dense MFMA GEMM (verified m89/m91 layout).
// ---------------------------------------------------------------------------
template <int K>
__global__ void __launch_bounds__(256, 2) gemm_bf16(
    const short* __restrict__ A, const short* __restrict__ BT,
    short* __restrict__ C, int N) {
  int lane = threadIdx.x & 63;
  int w = threadIdx.x >> 6;
  int m0 = blockIdx.x * 128 + (w & 1) * 64;
  int n0 = blockIdx.y * 128 + (w >> 1) * 64;
  int fr = lane & 15;
  int kg = lane >> 4;
  f32x4 acc[4][4] = {};
#pragma unroll
  for (int kc = 0; kc < K; kc += 32) {
    bf16x8 a[4], b[4];
#pragma unroll
    for (int i = 0; i < 4; i++) {
      a[i] = *(const bf16x8*)(A + (size_t)(m0 + i * 16 + fr) * K + kc + kg * 8);
      b[i] = *(const bf16x8*)(BT + (size_t)(n0 + i * 16 + fr) * K + kc + kg * 8);
    }
#pragma unroll
    for (int i = 0; i < 4; i++)
#pragma unroll
      for (int j = 0; j < 4; j++)
        acc[i][j] = __builtin_amdgcn_mfma_f32_16x16x32_bf16(a[i], b[j], acc[i][j], 0, 0, 0);
  }
#pragma unroll
  for (int i = 0; i < 4; i++) {
    int row = m0 + i * 16 + (lane >> 4) * 4;
#pragma unroll
    for (int j = 0; j < 4; j++) {
      int col = n0 + j * 16 + (lane & 15);
#pragma unroll
      for (int r = 0; r < 4; r++)
        C[(size_t)(row + r) * N + col] = f2b(acc[i][j][r]);
    }
  }
}

// ---------------------------------------------------------------------------
// Stage-4 dense conv (K=64, 2 couts/cell, fp32): wave per node, lane = cell.
// ---------------------------------------------------------------------------
__global__ void __launch_bounds__(256) conv_k64_c2(
    const float* __restrict__ x, const float* __restrict__ W4 /*[64][64][2]*/,
    float* __restrict__ Y4, int c0, int CC) {
  int lane = threadIdx.x & 63;
  int n = blockIdx.x * 4 + (threadIdx.x >> 6);
  float xv = x[(size_t)n * 64 + lane];
  int cell = c0 + lane;
  const float2* wr = (const float2*)(W4 + (size_t)cell * 128);
  float a0 = 0.f, a1 = 0.f;
#pragma unroll
  for (int k = 0; k < 64; k++) {
    float xk = __shfl(xv, k, 64);
    float2 wk = wr[k];
    a0 = fmaf(xk, wk.x, a0);
    a1 = fmaf(xk, wk.y, a1);
  }
  if (lane < CC)
    *(float2*)(Y4 + (size_t)n * (CC * 2) + lane * 2) = make_float2(a0, a1);
}

// ---------------------------------------------------------------------------
// Stage 1: FOUR waves per node. Waves 0-2 split fluid edges 3 ways (LDS
// combine); wave 3 does boundary conv + lin. Serial chain depth ~16 -> ~6.
// ---------------------------------------------------------------------------
__global__ void __launch_bounds__(256, 8) b1_stage1(
    const float* __restrict__ ff, const float* __restrict__ bfe,
    const float* __restrict__ fc0,
    const float* __restrict__ W0, const float* __restrict__ W1,
    const int* __restrict__ ftstart, const unsigned* __restrict__ fpk,
    const float4* __restrict__ fwt,
    const int* __restrict__ btstart, const unsigned* __restrict__ bpk,
    const float4* __restrict__ bwt,
    float* __restrict__ ans0, short* __restrict__ Xh96) {
  __shared__ float2 part[3][16];
  int lane = threadIdx.x & 63;
  int wid = threadIdx.x >> 6;
  int t = blockIdx.x;
  int q = lane >> 4;
  int p = lane & 15;
  int cofs = (q & 1) + (q >> 1) * 8;

  if (wid < 3) {
    // fluid third
    int s = ftstart[t], e1 = ftstart[t + 1];
    int len = e1 - s;
    int i0 = s + (len * wid) / 3;
    int i1 = s + (len * (wid + 1)) / 3;
    float2 acc = make_float2(0.f, 0.f);
    auto edge = [&](unsigned pk, float4 w4, float4 xv) {
      int cell = (int)(pk >> 14) + cofs;
      float wq = (q == 0) ? w4.x : (q == 1) ? w4.y : (q == 2) ? w4.z : w4.w;
      const float* Wc = W0 + cell * 128 + 2 * p;
      float2 k0 = *(const float2*)(Wc);
      float2 k1 = *(const float2*)(Wc + 32);
      float2 k2 = *(const float2*)(Wc + 64);
      float2 k3 = *(const float2*)(Wc + 96);
      acc.x = fmaf(wq, xv.x * k0.x + xv.y * k1.x + xv.z * k2.x + xv.w * k3.x, acc.x);
      acc.y = fmaf(wq, xv.x * k0.y + xv.y * k1.y + xv.z * k2.y + xv.w * k3.y, acc.y);
    };
    int idx = i0;
    for (; idx + 1 < i1; idx += 2) {
      unsigned pk0 = fpk[idx], pk1 = fpk[idx + 1];
      float4 w0 = fwt[idx], w1 = fwt[idx + 1];
      float4 x0 = *(const float4*)(ff + (size_t)(pk0 & 16383) * 4);
      float4 x1 = *(const float4*)(ff + (size_t)(pk1 & 16383) * 4);
      edge(pk0, w0, x0);
      edge(pk1, w1, x1);
    }
    if (idx < i1) {
      unsigned pk = fpk[idx];
      float4 w4 = fwt[idx];
      float4 xv = *(const float4*)(ff + (size_t)(pk & 16383) * 4);
      edge(pk, w4, xv);
    }
    acc.x += __shfl_xor(acc.x, 16, 64); acc.y += __shfl_xor(acc.y, 16, 64);
    acc.x += __shfl_xor(acc.x, 32, 64); acc.y += __shfl_xor(acc.y, 32, 64);
    if (lane < 16) part[wid][p] = acc;
  } else {
    // boundary conv + lin
    int s = btstart[t], e1 = btstart[t + 1];
    float2 acc = make_float2(0.f, 0.f);
    for (int idx = s; idx < e1; idx++) {
      unsigned pk = bpk[idx];
      float4 w4 = bwt[idx];
      float4 xv = *(const float4*)(bfe + (size_t)(pk & 16383) * 4);
      int cell = (int)(pk >> 14) + cofs;
      float wq = (q == 0) ? w4.x : (q == 1) ? w4.y : (q == 2) ? w4.z : w4.w;
      const float* Wc = W1 + cell * 128 + 2 * p;
      float2 k0 = *(const float2*)(Wc);
      float2 k1 = *(const float2*)(Wc + 32);
      float2 k2 = *(const float2*)(Wc + 64);
      float2 k3 = *(const float2*)(Wc + 96);
      acc.x = fmaf(wq, xv.x * k0.x + xv.y * k1.x + xv.z * k2.x + xv.w * k3.x, acc.x);
      acc.y = fmaf(wq, xv.x * k0.y + xv.y * k1.y + xv.z * k2.y + xv.w * k3.y, acc.y);
    }
    acc.x += __shfl_xor(acc.x, 16, 64); acc.y += __shfl_xor(acc.y, 16, 64);
    acc.x += __shfl_xor(acc.x, 32, 64); acc.y += __shfl_xor(acc.y, 32, 64);
    if (lane < 16) {
      acc.x = fmaxf(acc.x, 0.f); acc.y = fmaxf(acc.y, 0.f);
      *(float2*)(ans0 + (size_t)t * 96 + 64 + 2 * p) = acc;
      *(unsigned*)(Xh96 + (size_t)t * 96 + 64 + 2 * p) = pack2(acc.x, acc.y);
    } else if (lane < 32) {
      float4 fv = *(const float4*)(ff + (size_t)t * 4);
      float l0 = fv.x * fc0[2 * p] + fv.y * fc0[32 + 2 * p] +
                 fv.z * fc0[64 + 2 * p] + fv.w * fc0[96 + 2 * p];
      float l1 = fv.x * fc0[2 * p + 1] + fv.y * fc0[32 + 2 * p + 1] +
                 fv.z * fc0[64 + 2 * p + 1] + fv.w * fc0[96 + 2 * p + 1];
      l0 = fmaxf(l0, 0.f); l1 = fmaxf(l1, 0.f);
      *(float2*)(ans0 + (size_t)t * 96 + 2 * p) = make_float2(l0, l1);
      *(unsigned*)(Xh96 + (size_t)t * 96 + 2 * p) = pack2(l0, l1);
    }
  }
  __syncthreads();
  if (wid == 0 && lane < 16) {
    float2 f0 = part[0][p], f1 = part[1][p], f2 = part[2][p];
    float fx = fmaxf(f0.x + f1.x + f2.x, 0.f);
    float fy = fmaxf(f0.y + f1.y + f2.y, 0.f);
    *(float2*)(ans0 + (size_t)t * 96 + 32 + 2 * p) = make_float2(fx, fy);
    *(unsigned*)(Xh96 + (size_t)t * 96 + 32 + 2 * p) = pack2(fx, fy);
  }
}

// ---------------------------------------------------------------------------
// Phase B stages 2/3: TWO waves per target (edge range halved, LDS combine).
// Quad-width Y gather + folded fc GEMM (done by the half-1 wave).
// ---------------------------------------------------------------------------
template <int CIN, int RESID, int WBF16>
__global__ void __launch_bounds__(256, 8) b23(
    const float* __restrict__ xin, const float* __restrict__ fc,
    const int* __restrict__ ftstart, const unsigned* __restrict__ epk,
    const float4* __restrict__ ewt, const short* __restrict__ Y,
    const float* __restrict__ resid, float* __restrict__ dest,
    short* __restrict__ Xh64, int c0, int CC, int init, int fin) {
  __shared__ float4 part[4][16];
  int lane = threadIdx.x & 63;
  int wid = threadIdx.x >> 6;
  int t = __builtin_amdgcn_readfirstlane(blockIdx.x * 2 + (wid >> 1));
  int half = wid & 1;
  int q = lane >> 4;
  int sub = lane & 15;
  int cofs = (q & 1) + (q >> 1) * 8;
  int YW = CC * 64;
  float a0 = 0.f, a1 = 0.f, a2 = 0.f, a3 = 0.f;
  int s = __builtin_amdgcn_readfirstlane(ftstart[t]);
  int e1 = __builtin_amdgcn_readfirstlane(ftstart[t + 1]);
  int mid = s + ((e1 - s + 1) >> 1);
  int lo = half ? mid : s;
  int hi = half ? e1 : mid;
  if (init && half) {
    // fc partial over this quarter's k-range (+resid), in the shorter wave
    if (RESID) {
      if (q == 0) {
        float4 rd = *(const float4*)(resid + (size_t)t * 64 + 4 * sub);
        a0 = rd.x; a1 = rd.y; a2 = rd.z; a3 = rd.w;
      }
    }
    const float* xr = xin + (size_t)t * CIN;
#pragma unroll
    for (int kk = 0; kk < CIN / 4; kk++) {
      int k = q * (CIN / 4) + kk;
      float xv = xr[k];
      float4 fv = *(const float4*)(fc + (size_t)k * 64 + 4 * sub);
      a0 = fmaf(xv, fv.x, a0);
      a1 = fmaf(xv, fv.y, a1);
      a2 = fmaf(xv, fv.z, a2);
      a3 = fmaf(xv, fv.w, a3);
    }
  }
  int idx = lo;
  for (; idx + 3 < hi; idx += 4) {
    unsigned pk_[4];
    float4 w_[4];
    int cell_[4], src_[4];
    float wq_[4];
    uint2 r_[4];
#pragma unroll
    for (int j = 0; j < 4; j++) {
      pk_[j] = epk[idx + j];
      w_[j] = ewt[idx + j];
      src_[j] = pk_[j] & 16383;
      cell_[j] = (int)(pk_[j] >> 14) + cofs - c0;
      wq_[j] = (q == 0) ? w_[j].x : (q == 1) ? w_[j].y : (q == 2) ? w_[j].z : w_[j].w;
      r_[j] = make_uint2(0, 0);
      if ((unsigned)cell_[j] < (unsigned)CC)
        r_[j] = *(const uint2*)(Y + (size_t)src_[j] * YW + cell_[j] * 64 + 4 * sub);
    }
#pragma unroll
    for (int j = 0; j < 4; j++) {
      a0 = fmaf(wq_[j], b2f_lo(r_[j].x), a0);
      a1 = fmaf(wq_[j], b2f_hi(r_[j].x), a1);
      a2 = fmaf(wq_[j], b2f_lo(r_[j].y), a2);
      a3 = fmaf(wq_[j], b2f_hi(r_[j].y), a3);
    }
  }
  for (; idx < hi; idx++) {
    unsigned pk = epk[idx];
    float4 w4 = ewt[idx];
    int src = pk & 16383;
    int cell = (int)(pk >> 14) + cofs - c0;
    float wq = (q == 0) ? w4.x : (q == 1) ? w4.y : (q == 2) ? w4.z : w4.w;
    if ((unsigned)cell < (unsigned)CC) {
      uint2 r = *(const uint2*)(Y + (size_t)src * YW + cell * 64 + 4 * sub);
      a0 = fmaf(wq, b2f_lo(r.x), a0);
      a1 = fmaf(wq, b2f_hi(r.x), a1);
      a2 = fmaf(wq, b2f_lo(r.y), a2);
      a3 = fmaf(wq, b2f_hi(r.y), a3);
    }
  }
  a0 += __shfl_xor(a0, 16, 64); a1 += __shfl_xor(a1, 16, 64);
  a2 += __shfl_xor(a2, 16, 64); a3 += __shfl_xor(a3, 16, 64);
  a0 += __shfl_xor(a0, 32, 64); a1 += __shfl_xor(a1, 32, 64);
  a2 += __shfl_xor(a2, 32, 64); a3 += __shfl_xor(a3, 32, 64);
  if (lane < 16) part[wid][sub] = make_float4(a0, a1, a2, a3);
  __syncthreads();
  if (half == 0 && lane < 16) {
    float4 pa = part[wid][sub];
    float4 pb = part[wid + 1][sub];
    a0 = pa.x + pb.x; a1 = pa.y + pb.y; a2 = pa.z + pb.z; a3 = pa.w + pb.w;
    float4* dst = (float4*)(dest + (size_t)t * 64 + 4 * sub);
    if (!init) {
      float4 d = *dst;
      a0 += d.x; a1 += d.y; a2 += d.z; a3 += d.w;
    }
    if (fin) {
      a0 = fmaxf(a0, 0.f); a1 = fmaxf(a1, 0.f);
      a2 = fmaxf(a2, 0.f); a3 = fmaxf(a3, 0.f);
    }
    *dst = make_float4(a0, a1, a2, a3);
    if (WBF16 && fin) {
      uint2 pkd = make_uint2(pack2(a0, a1), pack2(a2, a3));
      *(uint2*)(Xh64 + (size_t)t * 64 + 4 * sub) = pkd;
    }
  }
}

// ---------------------------------------------------------------------------
// Phase B stage 4: out[t] = gather(Y4) + ans2@fc3 (lane-parallel slots).
// ---------------------------------------------------------------------------
__global__ void __launch_bounds__(256, 8) b4_stage4(
    const float* __restrict__ ans2, const float* __restrict__ fc3,
    const int* __restrict__ ftstart, const unsigned* __restrict__ epk,
    const float4* __restrict__ ewt, const float* __restrict__ Y4,
    float* __restrict__ partial, float* __restrict__ outp,
    int c0, int CC, int init, int fin) {
  int lane = threadIdx.x & 63;
  int t = blockIdx.x * 4 + (threadIdx.x >> 6);
  int s4 = ftstart[t] * 4, e4 = ftstart[t + 1] * 4;
  float m0 = 0.f, m1 = 0.f;
  for (int fq = s4 + lane; fq < e4; fq += 64) {
    int idx = fq >> 2, j = fq & 3;
    unsigned pk = epk[idx];
    float4 w4 = ewt[idx];
    int src = pk & 16383;
    int cell = (int)(pk >> 14) + (j & 1) + (j >> 1) * 8 - c0;
    float w = (j == 0) ? w4.x : (j == 1) ? w4.y : (j == 2) ? w4.z : w4.w;
    if ((unsigned)cell < (unsigned)CC) {
      float2 mm = *(const float2*)(Y4 + (size_t)src * (CC * 2) + cell * 2);
      m0 += w * mm.x;
      m1 += w * mm.y;
    }
  }
  if (init) {
    float a = ans2[(size_t)t * 64 + lane];
    m0 += a * fc3[lane * 2 + 0];
    m1 += a * fc3[lane * 2 + 1];
  }
#pragma unroll
  for (int off = 32; off > 0; off >>= 1) {
    m0 += __shfl_xor(m0, off, 64);
    m1 += __shfl_xor(m1, off, 64);
  }
  if (lane == 0) {
    if (!init) { m0 += partial[t * 2]; m1 += partial[t * 2 + 1]; }
    if (fin) { outp[t * 2] = m0; outp[t * 2 + 1] = m1; }
    else { partial[t * 2] = m0; partial[t * 2 + 1] = m1; }
  }
}

// ---------------------------------------------------------------------------
extern "C" void kernel_launch(void* const* d_in, const int* in_sizes, int n_in,
                              void* d_out, int out_size, void* d_ws, size_t ws_size,
                              hipStream_t stream) {
  const float* fp  = (const float*)d_in[0];
  const float* bp  = (const float*)d_in[1];
  const float* ff  = (const float*)d_in[2];
  const float* bfe = (const float*)d_in[3];
  const float* sup = (const float*)d_in[4];
  const int* fi  = (const int*)d_in[5];
  const int* fj  = (const int*)d_in[6];
  const int* bfi = (const int*)d_in[7];
  const int* bb  = (const int*)d_in[8];
  const float* W0 = (const float*)d_in[9];
  const float* W1 = (const float*)d_in[10];
  const float* W2 = (const float*)d_in[11];
  const float* W3 = (const float*)d_in[12];
  const float* W4 = (const float*)d_in[13];
  const float* fc0 = (const float*)d_in[14];
  const float* fc1 = (const float*)d_in[15];
  const float* fc2 = (const float*)d_in[16];
  const float* fc3 = (const float*)d_in[17];
  float* out = (float*)d_out;

  char* w = (char*)d_ws;
  size_t off = 0;
  auto alloc = [&](size_t bytes) {
    char* p = w + off;
    off += (bytes + 255) & ~size_t(255);
    return p;
  };
  float* ans0   = (float*)alloc((size_t)NF * 96 * 4);
  float* ans1   = (float*)alloc((size_t)NF * 64 * 4);
  float* ans2   = (float*)alloc((size_t)NF * 64 * 4);
  float* outpre = (float*)alloc((size_t)NF * 2 * 4);
  int* fthist  = (int*)alloc((size_t)NF * 4);
  int* bthist  = (int*)alloc((size_t)NF * 4);   // adjacent to fthist: one memset
  int* ftstart = (int*)alloc((size_t)(NF + 1) * 4);
  int* ftcur   = (int*)alloc((size_t)NF * 4);
  int* btstart = (int*)alloc((size_t)(NF + 1) * 4);
  int* btcur   = (int*)alloc((size_t)NF * 4);
  unsigned* fpk  = (unsigned*)alloc((size_t)EF * 4);
  float4* fwtP   = (float4*)alloc((size_t)EF * 16);
  unsigned* bpk  = (unsigned*)alloc((size_t)EB * 4);
  float4* bwtP   = (float4*)alloc((size_t)EB * 16);
  short* Xh96 = (short*)alloc((size_t)NF * 96 * 2);
  short* Xh64 = (short*)alloc((size_t)NF * 64 * 2);
  short* BT = (short*)alloc((size_t)4096 * 96 * 2);
  char* Yreg = w + off;
  size_t avail = (ws_size > off) ? (ws_size - off) : 0;
  size_t percell = (size_t)NF * 64 * 2;
  int CC = 64;
  while (CC > 8 && (size_t)CC * percell > avail) CC >>= 1;
  int S = 64 / CC;
  short* Y  = (short*)Yreg;
  float* Y4 = (float*)Yreg;

  hipMemsetAsync(fthist, 0, (size_t)NF * 8, stream);

  dual_hist<<<FBLK + BBLK, 256, 0, stream>>>(fi, bfi, fthist, bthist);
  csr_scan2<<<2, 1024, 0, stream>>>(fthist, bthist, ftstart, ftcur, btstart, btcur);
  dual_scatter_payload<<<FBLK + BBLK, 256, 0, stream>>>(fi, fj, bfi, bb, fp, bp, sup,
                                                        ftcur, btcur, fpk, fwtP, bpk, bwtP);

  // Stage 1: fused, 4 waves/node. Emits ans0 + bf16 Xh96.
  b1_stage1<<<NF, 256, 0, stream>>>(ff, bfe, fc0, W0, W1,
                                    ftstart, fpk, fwtP, btstart, bpk, bwtP,
                                    ans0, Xh96);
  // Stage 2: MFMA GEMM + gather. Emits ans1 + bf16 Xh64.
  buildBT<<<(4096 * 96 + 255) / 256, 256, 0, stream>>>(W2, BT, 96);
  for (int c = 0; c < S; c++) {
    int c0 = c * CC;
    gemm_bf16<96><<<dim3(NF / 128, CC * 64 / 128), 256, 0, stream>>>(
        Xh96, BT + (size_t)c0 * 64 * 96, Y, CC * 64);
    b23<96, 0, 1><<<NF / 2, 256, 0, stream>>>(ans0, fc1, ftstart, fpk, fwtP,
                                              Y, nullptr, ans1, Xh64,
                                              c0, CC, c == 0, c == S - 1);
  }
  // Stage 3
  buildBT<<<(4096 * 64 + 255) / 256, 256, 0, stream>>>(W3, BT, 64);
  for (int c = 0; c < S; c++) {
    int c0 = c * CC;
    gemm_bf16<64><<<dim3(NF / 128, CC * 64 / 128), 256, 0, stream>>>(
        Xh64, BT + (size_t)c0 * 64 * 64, Y, CC * 64);
    b23<64, 1, 0><<<NF / 2, 256, 0, stream>>>(ans1, fc2, ftstart, fpk, fwtP,
                                              Y, ans1, ans2, nullptr,
                                              c0, CC, c == 0, c == S - 1);
  }
  // Stage 4
  for (int c = 0; c < S; c++) {
    int c0 = c * CC;
    conv_k64_c2<<<NF / 4, 256, 0, stream>>>(ans2, W4, Y4, c0, CC);
    b4_stage4<<<NF / 4, 256, 0, stream>>>(ans2, fc3, ftstart, fpk, fwtP,
                                          Y4, outpre, out, c0, CC, c == 0, c == S - 1);
  }
}

// Round 11
// 415.627 us; speedup vs baseline: 1.0829x; 1.0829x over previous
//
#include <hip/hip_runtime.h>

#define NF 16384
#define NB 4096
#define EF 262144
#define EB 65536
#define FBLK 1024   // EF/256
#define BBLK 256    // EB/256

typedef __attribute__((ext_vector_type(8))) short bf16x8;
typedef __attribute__((ext_vector_type(4))) float f32x4;

__device__ __forceinline__ short f2b(float f) {
  unsigned u = __float_as_uint(f);
  u += 0x7fff + ((u >> 16) & 1);   // RNE
  return (short)(u >> 16);
}
__device__ __forceinline__ unsigned pack2(float lo, float hi) {
  return (unsigned)(unsigned short)f2b(lo) | ((unsigned)(unsigned short)f2b(hi) << 16);
}
__device__ __forceinline__ float b2f_lo(unsigned u) {
  return __uint_as_float(u << 16);
}
__device__ __forceinline__ float b2f_hi(unsigned u) {
  return __uint_as_float(u & 0xffff0000u);
}

// ---------------------------------------------------------------------------
// Target CSR: histogram (merged fluid+boundary).
// ---------------------------------------------------------------------------
__global__ void __launch_bounds__(256) dual_hist(const int* __restrict__ fi,
                                                 const int* __restrict__ bfi,
                                                 int* __restrict__ fhist,
                                                 int* __restrict__ bhist) {
  int bid = blockIdx.x;
  if (bid < FBLK) {
    int e = bid * 256 + threadIdx.x;
    atomicAdd(fhist + fi[e], 1);
  } else {
    int e = (bid - FBLK) * 256 + threadIdx.x;
    atomicAdd(bhist + bfi[e], 1);
  }
}

__global__ void __launch_bounds__(1024) csr_scan2(const int* __restrict__ fhist,
                                                  const int* __restrict__ bhist,
                                                  int* __restrict__ fstart, int* __restrict__ fcur,
                                                  int* __restrict__ bstart, int* __restrict__ bcur) {
  const int* hist = blockIdx.x ? bhist : fhist;
  int* start = blockIdx.x ? bstart : fstart;
  int* cursor = blockIdx.x ? bcur : fcur;
  __shared__ int wtot[16];
  int t = threadIdx.x;
  int lane = t & 63, wv = t >> 6;
  int base = t * 16;
  int vals[16];
  int s = 0;
#pragma unroll
  for (int k = 0; k < 16; k++) { vals[k] = hist[base + k]; s += vals[k]; }
  int ss = s;
  for (int off = 1; off < 64; off <<= 1) {
    int o = __shfl_up(ss, off, 64);
    if (lane >= off) ss += o;
  }
  if (lane == 63) wtot[wv] = ss;
  __syncthreads();
  if (t < 16) {
    int v = wtot[t];
    int vv = v;
    for (int off = 1; off < 16; off <<= 1) {
      int o = __shfl_up(vv, off, 64);
      if (t >= off) vv += o;
    }
    wtot[t] = vv - v;
  }
  __syncthreads();
  int run = ss - s + wtot[wv];
#pragma unroll
  for (int k = 0; k < 16; k++) { start[base + k] = run; cursor[base + k] = run; run += vals[k]; }
  if (t == 1023) start[16384] = run;
}

// ---------------------------------------------------------------------------
// Merged scatter + payload + tent-basis.
// ---------------------------------------------------------------------------
__global__ void __launch_bounds__(256) dual_scatter_payload(
    const int* __restrict__ fi, const int* __restrict__ fj,
    const int* __restrict__ bfi, const int* __restrict__ bb,
    const float* __restrict__ fp, const float* __restrict__ bp,
    const float* __restrict__ supportp,
    int* __restrict__ fcur, int* __restrict__ bcur,
    unsigned* __restrict__ fpk, float4* __restrict__ fwt,
    unsigned* __restrict__ bpk, float4* __restrict__ bwt) {
  int bid = blockIdx.x;
  bool fluid = bid < FBLK;
  int e = (fluid ? bid : bid - FBLK) * 256 + threadIdx.x;
  int ti = fluid ? fi[e] : bfi[e];
  int si = fluid ? fj[e] : bb[e];
  const float2* pT2 = (const float2*)fp;
  const float2* pS2 = fluid ? (const float2*)fp : (const float2*)bp;
  float sign = fluid ? -1.f : 1.f;
  float inv_sup = 1.0f / supportp[0];
  float2 pt = pT2[ti];
  float2 ps = pS2[si];
  // d = sign*(src-tgt)/support. (-1)*(+0) = -0 preserves reference signed
  // zeros for self-edges (atan2(-0,-0) = -pi).
  float dx = sign * ((ps.x - pt.x) * inv_sup);
  float dy = sign * ((ps.y - pt.y) * inv_sup);
  dx = fminf(fmaxf(dx, -1.f), 1.f);
  dy = fminf(fmaxf(dy, -1.f), 1.f);
  float r = sqrtf(dx * dx + dy * dy + 1e-12f);
  float theta;
  if (dx == 0.0f && dy == 0.0f) {
    float mag = __builtin_signbitf(dx) ? 3.14159265358979323846f : 0.0f;
    theta = __builtin_signbitf(dy) ? -mag : mag;
  } else {
    theta = atan2f(dy, dx);
  }
  float u = 2.f * r - 1.f;
  float v = theta * (1.f / 3.14159265358979323846f);
  float tu = (u + 1.f) * 3.5f;
  float tv = (v + 1.f) * 3.5f;
  int iu = min(max((int)floorf(tu), 0), 6);
  int iv = min(max((int)floorf(tv), 0), 6);
  float wu0 = fmaxf(0.f, 1.f - fabsf(tu - (float)iu));
  float wu1 = fmaxf(0.f, 1.f - fabsf(tu - (float)(iu + 1)));
  float wv0 = fmaxf(0.f, 1.f - fabsf(tv - (float)iv));
  float wv1 = fmaxf(0.f, 1.f - fabsf(tv - (float)(iv + 1)));
  unsigned pk = (unsigned)si | ((unsigned)(iu * 8 + iv) << 14);
  float4 w4 = make_float4(wu0 * wv0, wu0 * wv1, wu1 * wv0, wu1 * wv1);
  if (fluid) {
    int p = atomicAdd(fcur + ti, 1);
    fpk[p] = pk; fwt[p] = w4;
  } else {
    int p = atomicAdd(bcur + ti, 1);
    bpk[p] = pk; bwt[p] = w4;
  }
}

__global__ void __launch_bounds__(256) buildBT(const float* __restrict__ W,
                                               short* __restrict__ BT, int K) {
  int tid = blockIdx.x * 256 + threadIdx.x;
  if (tid >= 4096 * K) return;
  int k = tid % K, n = tid / K;
  BT[tid] = f2b(W[((size_t)(n >> 6) * K + k) * 64 + (n & 63)]);
}

// ---------------------------------------------------------------------------
// Dense MFMA GEMM (verified m89/m91 layout).
// ---------------------------------------------------------------------------
template <int K>
__global__ void __launch_bounds__(256, 2) gemm_bf16(
    const short* __restrict__ A, const short* __restrict__ BT,
    short* __restrict__ C, int N) {
  int lane = threadIdx.x & 63;
  int w = threadIdx.x >> 6;
  int m0 = blockIdx.x * 128 + (w & 1) * 64;
  int n0 = blockIdx.y * 128 + (w >> 1) * 64;
  int fr = lane & 15;
  int kg = lane >> 4;
  f32x4 acc[4][4] = {};
#pragma unroll
  for (int kc = 0; kc < K; kc += 32) {
    bf16x8 a[4], b[4];
#pragma unroll
    for (int i = 0; i < 4; i++) {
      a[i] = *(const bf16x8*)(A + (size_t)(m0 + i * 16 + fr) * K + kc + kg * 8);
      b[i] = *(const bf16x8*)(BT + (size_t)(n0 + i * 16 + fr) * K + kc + kg * 8);
    }
#pragma unroll
    for (int i = 0; i < 4; i++)
#pragma unroll
      for (int j = 0; j < 4; j++)
        acc[i][j] = __builtin_amdgcn_mfma_f32_16x16x32_bf16(a[i], b[j], acc[i][j], 0, 0, 0);
  }
#pragma unroll
  for (int i = 0; i < 4; i++) {
    int row = m0 + i * 16 + (lane >> 4) * 4;
#pragma unroll
    for (int j = 0; j < 4; j++) {
      int col = n0 + j * 16 + (lane & 15);
#pragma unroll
      for (int r = 0; r < 4; r++)
        C[(size_t)(row + r) * N + col] = f2b(acc[i][j][r]);
    }
  }
}

// ---------------------------------------------------------------------------
// Stage-4 dense conv (K=64, 2 couts/cell, fp32): wave per node, lane = cell.
// ---------------------------------------------------------------------------
__global__ void __launch_bounds__(256) conv_k64_c2(
    const float* __restrict__ x, const float* __restrict__ W4 /*[64][64][2]*/,
    float* __restrict__ Y4, int c0, int CC) {
  int lane = threadIdx.x & 63;
  int n = blockIdx.x * 4 + (threadIdx.x >> 6);
  float xv = x[(size_t)n * 64 + lane];
  int cell = c0 + lane;
  const float2* wr = (const float2*)(W4 + (size_t)cell * 128);
  float a0 = 0.f, a1 = 0.f;
#pragma unroll
  for (int k = 0; k < 64; k++) {
    float xk = __shfl(xv, k, 64);
    float2 wk = wr[k];
    a0 = fmaf(xk, wk.x, a0);
    a1 = fmaf(xk, wk.y, a1);
  }
  if (lane < CC)
    *(float2*)(Y4 + (size_t)n * (CC * 2) + lane * 2) = make_float2(a0, a1);
}

// ---------------------------------------------------------------------------
// Stage 1: FOUR waves per node (round-10 form — best measured). Waves 0-2
// split fluid edges; wave 3 does boundary conv + lin; LDS combine.
// ---------------------------------------------------------------------------
__global__ void __launch_bounds__(256, 8) b1_stage1(
    const float* __restrict__ ff, const float* __restrict__ bfe,
    const float* __restrict__ fc0,
    const float* __restrict__ W0, const float* __restrict__ W1,
    const int* __restrict__ ftstart, const unsigned* __restrict__ fpk,
    const float4* __restrict__ fwt,
    const int* __restrict__ btstart, const unsigned* __restrict__ bpk,
    const float4* __restrict__ bwt,
    float* __restrict__ ans0, short* __restrict__ Xh96) {
  __shared__ float2 part[3][16];
  int lane = threadIdx.x & 63;
  int wid = threadIdx.x >> 6;
  int t = blockIdx.x;
  int q = lane >> 4;
  int p = lane & 15;
  int cofs = (q & 1) + (q >> 1) * 8;

  if (wid < 3) {
    int s = ftstart[t], e1 = ftstart[t + 1];
    int len = e1 - s;
    int i0 = s + (len * wid) / 3;
    int i1 = s + (len * (wid + 1)) / 3;
    float2 acc = make_float2(0.f, 0.f);
    auto edge = [&](unsigned pk, float4 w4, float4 xv) {
      int cell = (int)(pk >> 14) + cofs;
      float wq = (q == 0) ? w4.x : (q == 1) ? w4.y : (q == 2) ? w4.z : w4.w;
      const float* Wc = W0 + cell * 128 + 2 * p;
      float2 k0 = *(const float2*)(Wc);
      float2 k1 = *(const float2*)(Wc + 32);
      float2 k2 = *(const float2*)(Wc + 64);
      float2 k3 = *(const float2*)(Wc + 96);
      acc.x = fmaf(wq, xv.x * k0.x + xv.y * k1.x + xv.z * k2.x + xv.w * k3.x, acc.x);
      acc.y = fmaf(wq, xv.x * k0.y + xv.y * k1.y + xv.z * k2.y + xv.w * k3.y, acc.y);
    };
    int idx = i0;
    for (; idx + 1 < i1; idx += 2) {
      unsigned pk0 = fpk[idx], pk1 = fpk[idx + 1];
      float4 w0 = fwt[idx], w1 = fwt[idx + 1];
      float4 x0 = *(const float4*)(ff + (size_t)(pk0 & 16383) * 4);
      float4 x1 = *(const float4*)(ff + (size_t)(pk1 & 16383) * 4);
      edge(pk0, w0, x0);
      edge(pk1, w1, x1);
    }
    if (idx < i1) {
      unsigned pk = fpk[idx];
      float4 w4 = fwt[idx];
      float4 xv = *(const float4*)(ff + (size_t)(pk & 16383) * 4);
      edge(pk, w4, xv);
    }
    acc.x += __shfl_xor(acc.x, 16, 64); acc.y += __shfl_xor(acc.y, 16, 64);
    acc.x += __shfl_xor(acc.x, 32, 64); acc.y += __shfl_xor(acc.y, 32, 64);
    if (lane < 16) part[wid][p] = acc;
  } else {
    int s = btstart[t], e1 = btstart[t + 1];
    float2 acc = make_float2(0.f, 0.f);
    for (int idx = s; idx < e1; idx++) {
      unsigned pk = bpk[idx];
      float4 w4 = bwt[idx];
      float4 xv = *(const float4*)(bfe + (size_t)(pk & 16383) * 4);
      int cell = (int)(pk >> 14) + cofs;
      float wq = (q == 0) ? w4.x : (q == 1) ? w4.y : (q == 2) ? w4.z : w4.w;
      const float* Wc = W1 + cell * 128 + 2 * p;
      float2 k0 = *(const float2*)(Wc);
      float2 k1 = *(const float2*)(Wc + 32);
      float2 k2 = *(const float2*)(Wc + 64);
      float2 k3 = *(const float2*)(Wc + 96);
      acc.x = fmaf(wq, xv.x * k0.x + xv.y * k1.x + xv.z * k2.x + xv.w * k3.x, acc.x);
      acc.y = fmaf(wq, xv.x * k0.y + xv.y * k1.y + xv.z * k2.y + xv.w * k3.y, acc.y);
    }
    acc.x += __shfl_xor(acc.x, 16, 64); acc.y += __shfl_xor(acc.y, 16, 64);
    acc.x += __shfl_xor(acc.x, 32, 64); acc.y += __shfl_xor(acc.y, 32, 64);
    if (lane < 16) {
      acc.x = fmaxf(acc.x, 0.f); acc.y = fmaxf(acc.y, 0.f);
      *(float2*)(ans0 + (size_t)t * 96 + 64 + 2 * p) = acc;
      *(unsigned*)(Xh96 + (size_t)t * 96 + 64 + 2 * p) = pack2(acc.x, acc.y);
    } else if (lane < 32) {
      float4 fv = *(const float4*)(ff + (size_t)t * 4);
      float l0 = fv.x * fc0[2 * p] + fv.y * fc0[32 + 2 * p] +
                 fv.z * fc0[64 + 2 * p] + fv.w * fc0[96 + 2 * p];
      float l1 = fv.x * fc0[2 * p + 1] + fv.y * fc0[32 + 2 * p + 1] +
                 fv.z * fc0[64 + 2 * p + 1] + fv.w * fc0[96 + 2 * p + 1];
      l0 = fmaxf(l0, 0.f); l1 = fmaxf(l1, 0.f);
      *(float2*)(ans0 + (size_t)t * 96 + 2 * p) = make_float2(l0, l1);
      *(unsigned*)(Xh96 + (size_t)t * 96 + 2 * p) = pack2(l0, l1);
    }
  }
  __syncthreads();
  if (wid == 0 && lane < 16) {
    float2 f0 = part[0][p], f1 = part[1][p], f2 = part[2][p];
    float fx = fmaxf(f0.x + f1.x + f2.x, 0.f);
    float fy = fmaxf(f0.y + f1.y + f2.y, 0.f);
    *(float2*)(ans0 + (size_t)t * 96 + 32 + 2 * p) = make_float2(fx, fy);
    *(unsigned*)(Xh96 + (size_t)t * 96 + 32 + 2 * p) = pack2(fx, fy);
  }
}

// ---------------------------------------------------------------------------
// Phase B stages 2/3 (round-9 structure: ONE wave per target, no LDS) with
// 8-edge unroll for memory-level parallelism. Quad-width Y gather + folded
// fc GEMM; payload stream scalarized via readfirstlane'd node id.
// ---------------------------------------------------------------------------
template <int CIN, int RESID, int WBF16>
__global__ void __launch_bounds__(256, 4) b23(
    const float* __restrict__ xin, const float* __restrict__ fc,
    const int* __restrict__ ftstart, const unsigned* __restrict__ epk,
    const float4* __restrict__ ewt, const short* __restrict__ Y,
    const float* __restrict__ resid, float* __restrict__ dest,
    short* __restrict__ Xh64, int c0, int CC, int init, int fin) {
  int lane = threadIdx.x & 63;
  int t = __builtin_amdgcn_readfirstlane(blockIdx.x * 4 + (threadIdx.x >> 6));
  int q = lane >> 4;
  int sub = lane & 15;
  int cofs = (q & 1) + (q >> 1) * 8;
  int YW = CC * 64;
  float a0 = 0.f, a1 = 0.f, a2 = 0.f, a3 = 0.f;
  if (init) {
    const float* xr = xin + (size_t)t * CIN;
#pragma unroll
    for (int kk = 0; kk < CIN / 4; kk++) {
      int k = q * (CIN / 4) + kk;
      float xv = xr[k];
      float4 fv = *(const float4*)(fc + (size_t)k * 64 + 4 * sub);
      a0 = fmaf(xv, fv.x, a0);
      a1 = fmaf(xv, fv.y, a1);
      a2 = fmaf(xv, fv.z, a2);
      a3 = fmaf(xv, fv.w, a3);
    }
  }
  int s = __builtin_amdgcn_readfirstlane(ftstart[t]);
  int e1 = __builtin_amdgcn_readfirstlane(ftstart[t + 1]);
  int idx = s;
  for (; idx + 7 < e1; idx += 8) {
    unsigned pk_[8];
    float wq_[8];
    uint2 r_[8];
#pragma unroll
    for (int j = 0; j < 8; j++) {
      pk_[j] = epk[idx + j];
      float4 w4 = ewt[idx + j];
      int src = pk_[j] & 16383;
      int cell = (int)(pk_[j] >> 14) + cofs - c0;
      wq_[j] = (q == 0) ? w4.x : (q == 1) ? w4.y : (q == 2) ? w4.z : w4.w;
      r_[j] = make_uint2(0, 0);
      if ((unsigned)cell < (unsigned)CC)
        r_[j] = *(const uint2*)(Y + (size_t)src * YW + cell * 64 + 4 * sub);
    }
#pragma unroll
    for (int j = 0; j < 8; j++) {
      a0 = fmaf(wq_[j], b2f_lo(r_[j].x), a0);
      a1 = fmaf(wq_[j], b2f_hi(r_[j].x), a1);
      a2 = fmaf(wq_[j], b2f_lo(r_[j].y), a2);
      a3 = fmaf(wq_[j], b2f_hi(r_[j].y), a3);
    }
  }
  for (; idx + 3 < e1; idx += 4) {
    unsigned pk_[4];
    float wq_[4];
    uint2 r_[4];
#pragma unroll
    for (int j = 0; j < 4; j++) {
      pk_[j] = epk[idx + j];
      float4 w4 = ewt[idx + j];
      int src = pk_[j] & 16383;
      int cell = (int)(pk_[j] >> 14) + cofs - c0;
      wq_[j] = (q == 0) ? w4.x : (q == 1) ? w4.y : (q == 2) ? w4.z : w4.w;
      r_[j] = make_uint2(0, 0);
      if ((unsigned)cell < (unsigned)CC)
        r_[j] = *(const uint2*)(Y + (size_t)src * YW + cell * 64 + 4 * sub);
    }
#pragma unroll
    for (int j = 0; j < 4; j++) {
      a0 = fmaf(wq_[j], b2f_lo(r_[j].x), a0);
      a1 = fmaf(wq_[j], b2f_hi(r_[j].x), a1);
      a2 = fmaf(wq_[j], b2f_lo(r_[j].y), a2);
      a3 = fmaf(wq_[j], b2f_hi(r_[j].y), a3);
    }
  }
  for (; idx < e1; idx++) {
    unsigned pk = epk[idx];
    float4 w4 = ewt[idx];
    int src = pk & 16383;
    int cell = (int)(pk >> 14) + cofs - c0;
    float wq = (q == 0) ? w4.x : (q == 1) ? w4.y : (q == 2) ? w4.z : w4.w;
    if ((unsigned)cell < (unsigned)CC) {
      uint2 r = *(const uint2*)(Y + (size_t)src * YW + cell * 64 + 4 * sub);
      a0 = fmaf(wq, b2f_lo(r.x), a0);
      a1 = fmaf(wq, b2f_hi(r.x), a1);
      a2 = fmaf(wq, b2f_lo(r.y), a2);
      a3 = fmaf(wq, b2f_hi(r.y), a3);
    }
  }
  a0 += __shfl_xor(a0, 16, 64); a1 += __shfl_xor(a1, 16, 64);
  a2 += __shfl_xor(a2, 16, 64); a3 += __shfl_xor(a3, 16, 64);
  a0 += __shfl_xor(a0, 32, 64); a1 += __shfl_xor(a1, 32, 64);
  a2 += __shfl_xor(a2, 32, 64); a3 += __shfl_xor(a3, 32, 64);
  if (lane < 16) {
    float4* dst = (float4*)(dest + (size_t)t * 64 + 4 * sub);
    if (!init) {
      float4 d = *dst;
      a0 += d.x; a1 += d.y; a2 += d.z; a3 += d.w;
    }
    if (RESID && init) {
      float4 rd = *(const float4*)(resid + (size_t)t * 64 + 4 * sub);
      a0 += rd.x; a1 += rd.y; a2 += rd.z; a3 += rd.w;
    }
    if (fin) {
      a0 = fmaxf(a0, 0.f); a1 = fmaxf(a1, 0.f);
      a2 = fmaxf(a2, 0.f); a3 = fmaxf(a3, 0.f);
    }
    *dst = make_float4(a0, a1, a2, a3);
    if (WBF16 && fin) {
      uint2 pkd = make_uint2(pack2(a0, a1), pack2(a2, a3));
      *(uint2*)(Xh64 + (size_t)t * 64 + 4 * sub) = pkd;
    }
  }
}

// ---------------------------------------------------------------------------
// Phase B stage 4: out[t] = gather(Y4) + ans2@fc3 (lane-parallel slots).
// ---------------------------------------------------------------------------
__global__ void __launch_bounds__(256, 8) b4_stage4(
    const float* __restrict__ ans2, const float* __restrict__ fc3,
    const int* __restrict__ ftstart, const unsigned* __restrict__ epk,
    const float4* __restrict__ ewt, const float* __restrict__ Y4,
    float* __restrict__ partial, float* __restrict__ outp,
    int c0, int CC, int init, int fin) {
  int lane = threadIdx.x & 63;
  int t = blockIdx.x * 4 + (threadIdx.x >> 6);
  int s4 = ftstart[t] * 4, e4 = ftstart[t + 1] * 4;
  float m0 = 0.f, m1 = 0.f;
  for (int fq = s4 + lane; fq < e4; fq += 64) {
    int idx = fq >> 2, j = fq & 3;
    unsigned pk = epk[idx];
    float4 w4 = ewt[idx];
    int src = pk & 16383;
    int cell = (int)(pk >> 14) + (j & 1) + (j >> 1) * 8 - c0;
    float w = (j == 0) ? w4.x : (j == 1) ? w4.y : (j == 2) ? w4.z : w4.w;
    if ((unsigned)cell < (unsigned)CC) {
      float2 mm = *(const float2*)(Y4 + (size_t)src * (CC * 2) + cell * 2);
      m0 += w * mm.x;
      m1 += w * mm.y;
    }
  }
  if (init) {
    float a = ans2[(size_t)t * 64 + lane];
    m0 += a * fc3[lane * 2 + 0];
    m1 += a * fc3[lane * 2 + 1];
  }
#pragma unroll
  for (int off = 32; off > 0; off >>= 1) {
    m0 += __shfl_xor(m0, off, 64);
    m1 += __shfl_xor(m1, off, 64);
  }
  if (lane == 0) {
    if (!init) { m0 += partial[t * 2]; m1 += partial[t * 2 + 1]; }
    if (fin) { outp[t * 2] = m0; outp[t * 2 + 1] = m1; }
    else { partial[t * 2] = m0; partial[t * 2 + 1] = m1; }
  }
}

// ---------------------------------------------------------------------------
extern "C" void kernel_launch(void* const* d_in, const int* in_sizes, int n_in,
                              void* d_out, int out_size, void* d_ws, size_t ws_size,
                              hipStream_t stream) {
  const float* fp  = (const float*)d_in[0];
  const float* bp  = (const float*)d_in[1];
  const float* ff  = (const float*)d_in[2];
  const float* bfe = (const float*)d_in[3];
  const float* sup = (const float*)d_in[4];
  const int* fi  = (const int*)d_in[5];
  const int* fj  = (const int*)d_in[6];
  const int* bfi = (const int*)d_in[7];
  const int* bb  = (const int*)d_in[8];
  const float* W0 = (const float*)d_in[9];
  const float* W1 = (const float*)d_in[10];
  const float* W2 = (const float*)d_in[11];
  const float* W3 = (const float*)d_in[12];
  const float* W4 = (const float*)d_in[13];
  const float* fc0 = (const float*)d_in[14];
  const float* fc1 = (const float*)d_in[15];
  const float* fc2 = (const float*)d_in[16];
  const float* fc3 = (const float*)d_in[17];
  float* out = (float*)d_out;

  char* w = (char*)d_ws;
  size_t off = 0;
  auto alloc = [&](size_t bytes) {
    char* p = w + off;
    off += (bytes + 255) & ~size_t(255);
    return p;
  };
  float* ans0   = (float*)alloc((size_t)NF * 96 * 4);
  float* ans1   = (float*)alloc((size_t)NF * 64 * 4);
  float* ans2   = (float*)alloc((size_t)NF * 64 * 4);
  float* outpre = (float*)alloc((size_t)NF * 2 * 4);
  int* fthist  = (int*)alloc((size_t)NF * 4);
  int* bthist  = (int*)alloc((size_t)NF * 4);   // adjacent to fthist: one memset
  int* ftstart = (int*)alloc((size_t)(NF + 1) * 4);
  int* ftcur   = (int*)alloc((size_t)NF * 4);
  int* btstart = (int*)alloc((size_t)(NF + 1) * 4);
  int* btcur   = (int*)alloc((size_t)NF * 4);
  unsigned* fpk  = (unsigned*)alloc((size_t)EF * 4);
  float4* fwtP   = (float4*)alloc((size_t)EF * 16);
  unsigned* bpk  = (unsigned*)alloc((size_t)EB * 4);
  float4* bwtP   = (float4*)alloc((size_t)EB * 16);
  short* Xh96 = (short*)alloc((size_t)NF * 96 * 2);
  short* Xh64 = (short*)alloc((size_t)NF * 64 * 2);
  short* BT = (short*)alloc((size_t)4096 * 96 * 2);
  char* Yreg = w + off;
  size_t avail = (ws_size > off) ? (ws_size - off) : 0;
  size_t percell = (size_t)NF * 64 * 2;
  int CC = 64;
  while (CC > 8 && (size_t)CC * percell > avail) CC >>= 1;
  int S = 64 / CC;
  short* Y  = (short*)Yreg;
  float* Y4 = (float*)Yreg;

  hipMemsetAsync(fthist, 0, (size_t)NF * 8, stream);

  dual_hist<<<FBLK + BBLK, 256, 0, stream>>>(fi, bfi, fthist, bthist);
  csr_scan2<<<2, 1024, 0, stream>>>(fthist, bthist, ftstart, ftcur, btstart, btcur);
  dual_scatter_payload<<<FBLK + BBLK, 256, 0, stream>>>(fi, fj, bfi, bb, fp, bp, sup,
                                                        ftcur, btcur, fpk, fwtP, bpk, bwtP);

  // Stage 1: fused, 4 waves/node. Emits ans0 + bf16 Xh96.
  b1_stage1<<<NF, 256, 0, stream>>>(ff, bfe, fc0, W0, W1,
                                    ftstart, fpk, fwtP, btstart, bpk, bwtP,
                                    ans0, Xh96);
  // Stage 2: MFMA GEMM + gather. Emits ans1 + bf16 Xh64.
  buildBT<<<(4096 * 96 + 255) / 256, 256, 0, stream>>>(W2, BT, 96);
  for (int c = 0; c < S; c++) {
    int c0 = c * CC;
    gemm_bf16<96><<<dim3(NF / 128, CC * 64 / 128), 256, 0, stream>>>(
        Xh96, BT + (size_t)c0 * 64 * 96, Y, CC * 64);
    b23<96, 0, 1><<<NF / 4, 256, 0, stream>>>(ans0, fc1, ftstart, fpk, fwtP,
                                              Y, nullptr, ans1, Xh64,
                                              c0, CC, c == 0, c == S - 1);
  }
  // Stage 3
  buildBT<<<(4096 * 64 + 255) / 256, 256, 0, stream>>>(W3, BT, 64);
  for (int c = 0; c < S; c++) {
    int c0 = c * CC;
    gemm_bf16<64><<<dim3(NF / 128, CC * 64 / 128), 256, 0, stream>>>(
        Xh64, BT + (size_t)c0 * 64 * 64, Y, CC * 64);
    b23<64, 1, 0><<<NF / 4, 256, 0, stream>>>(ans1, fc2, ftstart, fpk, fwtP,
                                              Y, ans1, ans2, nullptr,
                                              c0, CC, c == 0, c == S - 1);
  }
  // Stage 4
  for (int c = 0; c < S; c++) {
    int c0 = c * CC;
    conv_k64_c2<<<NF / 4, 256, 0, stream>>>(ans2, W4, Y4, c0, CC);
    b4_stage4<<<NF / 4, 256, 0, stream>>>(ans2, fc3, ftstart, fpk, fwtP,
                                          Y4, outpre, out, c0, CC, c == 0, c == S - 1);
  }
}

// Round 12
// 372.838 us; speedup vs baseline: 1.2072x; 1.1148x over previous
//
#include <hip/hip_runtime.h>

#define NF 16384
#define NB 4096
#define EF 262144
#define EB 65536
#define FBLK 1024   // EF/256
#define BBLK 256    // EB/256

typedef __attribute__((ext_vector_type(8))) short bf16x8;
typedef __attribute__((ext_vector_type(4))) float f32x4;

__device__ __forceinline__ short f2b(float f) {
  unsigned u = __float_as_uint(f);
  u += 0x7fff + ((u >> 16) & 1);   // RNE
  return (short)(u >> 16);
}
__device__ __forceinline__ unsigned pack2(float lo, float hi) {
  return (unsigned)(unsigned short)f2b(lo) | ((unsigned)(unsigned short)f2b(hi) << 16);
}
__device__ __forceinline__ float b2f_lo(unsigned u) {
  return __uint_as_float(u << 16);
}
__device__ __forceinline__ float b2f_hi(unsigned u) {
  return __uint_as_float(u & 0xffff0000u);
}

// ---------------------------------------------------------------------------
// Target CSR: histogram (merged fluid+boundary).
// ---------------------------------------------------------------------------
__global__ void __launch_bounds__(256) dual_hist(const int* __restrict__ fi,
                                                 const int* __restrict__ bfi,
                                                 int* __restrict__ fhist,
                                                 int* __restrict__ bhist) {
  int bid = blockIdx.x;
  if (bid < FBLK) {
    int e = bid * 256 + threadIdx.x;
    atomicAdd(fhist + fi[e], 1);
  } else {
    int e = (bid - FBLK) * 256 + threadIdx.x;
    atomicAdd(bhist + bfi[e], 1);
  }
}

__global__ void __launch_bounds__(1024) csr_scan2(const int* __restrict__ fhist,
                                                  const int* __restrict__ bhist,
                                                  int* __restrict__ fstart, int* __restrict__ fcur,
                                                  int* __restrict__ bstart, int* __restrict__ bcur) {
  const int* hist = blockIdx.x ? bhist : fhist;
  int* start = blockIdx.x ? bstart : fstart;
  int* cursor = blockIdx.x ? bcur : fcur;
  __shared__ int wtot[16];
  int t = threadIdx.x;
  int lane = t & 63, wv = t >> 6;
  int base = t * 16;
  int vals[16];
  int s = 0;
#pragma unroll
  for (int k = 0; k < 16; k++) { vals[k] = hist[base + k]; s += vals[k]; }
  int ss = s;
  for (int off = 1; off < 64; off <<= 1) {
    int o = __shfl_up(ss, off, 64);
    if (lane >= off) ss += o;
  }
  if (lane == 63) wtot[wv] = ss;
  __syncthreads();
  if (t < 16) {
    int v = wtot[t];
    int vv = v;
    for (int off = 1; off < 16; off <<= 1) {
      int o = __shfl_up(vv, off, 64);
      if (t >= off) vv += o;
    }
    wtot[t] = vv - v;
  }
  __syncthreads();
  int run = ss - s + wtot[wv];
#pragma unroll
  for (int k = 0; k < 16; k++) { start[base + k] = run; cursor[base + k] = run; run += vals[k]; }
  if (t == 1023) start[16384] = run;
}

// ---------------------------------------------------------------------------
// Merged scatter + payload + tent-basis.
// ---------------------------------------------------------------------------
__global__ void __launch_bounds__(256) dual_scatter_payload(
    const int* __restrict__ fi, const int* __restrict__ fj,
    const int* __restrict__ bfi, const int* __restrict__ bb,
    const float* __restrict__ fp, const float* __restrict__ bp,
    const float* __restrict__ supportp,
    int* __restrict__ fcur, int* __restrict__ bcur,
    unsigned* __restrict__ fpk, float4* __restrict__ fwt,
    unsigned* __restrict__ bpk, float4* __restrict__ bwt) {
  int bid = blockIdx.x;
  bool fluid = bid < FBLK;
  int e = (fluid ? bid : bid - FBLK) * 256 + threadIdx.x;
  int ti = fluid ? fi[e] : bfi[e];
  int si = fluid ? fj[e] : bb[e];
  const float2* pT2 = (const float2*)fp;
  const float2* pS2 = fluid ? (const float2*)fp : (const float2*)bp;
  float sign = fluid ? -1.f : 1.f;
  float inv_sup = 1.0f / supportp[0];
  float2 pt = pT2[ti];
  float2 ps = pS2[si];
  // d = sign*(src-tgt)/support. (-1)*(+0) = -0 preserves reference signed
  // zeros for self-edges (atan2(-0,-0) = -pi).
  float dx = sign * ((ps.x - pt.x) * inv_sup);
  float dy = sign * ((ps.y - pt.y) * inv_sup);
  dx = fminf(fmaxf(dx, -1.f), 1.f);
  dy = fminf(fmaxf(dy, -1.f), 1.f);
  float r = sqrtf(dx * dx + dy * dy + 1e-12f);
  float theta;
  if (dx == 0.0f && dy == 0.0f) {
    float mag = __builtin_signbitf(dx) ? 3.14159265358979323846f : 0.0f;
    theta = __builtin_signbitf(dy) ? -mag : mag;
  } else {
    theta = atan2f(dy, dx);
  }
  float u = 2.f * r - 1.f;
  float v = theta * (1.f / 3.14159265358979323846f);
  float tu = (u + 1.f) * 3.5f;
  float tv = (v + 1.f) * 3.5f;
  int iu = min(max((int)floorf(tu), 0), 6);
  int iv = min(max((int)floorf(tv), 0), 6);
  float wu0 = fmaxf(0.f, 1.f - fabsf(tu - (float)iu));
  float wu1 = fmaxf(0.f, 1.f - fabsf(tu - (float)(iu + 1)));
  float wv0 = fmaxf(0.f, 1.f - fabsf(tv - (float)iv));
  float wv1 = fmaxf(0.f, 1.f - fabsf(tv - (float)(iv + 1)));
  unsigned pk = (unsigned)si | ((unsigned)(iu * 8 + iv) << 14);
  float4 w4 = make_float4(wu0 * wv0, wu0 * wv1, wu1 * wv0, wu1 * wv1);
  if (fluid) {
    int p = atomicAdd(fcur + ti, 1);
    fpk[p] = pk; fwt[p] = w4;
  } else {
    int p = atomicAdd(bcur + ti, 1);
    bpk[p] = pk; bwt[p] = w4;
  }
}

__global__ void __launch_bounds__(256) buildBT(const float* __restrict__ W,
                                               short* __restrict__ BT, int K) {
  int tid = blockIdx.x * 256 + threadIdx.x;
  if (tid >= 4096 * K) return;
  int k = tid % K, n = tid / K;
  BT[tid] = f2b(W[((size_t)(n >> 6) * K + k) * 64 + (n & 63)]);
}

// ---------------------------------------------------------------------------
// Dense MFMA GEMM, LDS-staged tiles (conflict-free padded rows, 16B aligned).
// ---------------------------------------------------------------------------
template <int K>
__global__ void __launch_bounds__(256, 2) gemm_bf16(
    const short* __restrict__ A, const short* __restrict__ BT,
    short* __restrict__ C, int N) {
  constexpr int KP = K + 8;  // padded row (shorts): 16B-aligned, 2-way-bank only
  __shared__ __align__(16) short Al[128 * KP];
  __shared__ __align__(16) short Bl[128 * KP];
  int tid = threadIdx.x;
  int lane = tid & 63;
  int w = tid >> 6;
  int m0b = blockIdx.x * 128;
  int n0b = blockIdx.y * 128;
  constexpr int ROWV = K / 8;  // float4s per row
  for (int f = tid; f < 128 * ROWV; f += 256) {
    int r = f / ROWV, c = f % ROWV;
    *(float4*)(Al + r * KP + c * 8) = *(const float4*)(A + (size_t)(m0b + r) * K + c * 8);
    *(float4*)(Bl + r * KP + c * 8) = *(const float4*)(BT + (size_t)(n0b + r) * K + c * 8);
  }
  __syncthreads();
  int m0 = (w & 1) * 64;
  int n0 = (w >> 1) * 64;
  int fr = lane & 15;
  int kg = lane >> 4;
  f32x4 acc[4][4] = {};
#pragma unroll
  for (int kc = 0; kc < K; kc += 32) {
    bf16x8 a[4], b[4];
#pragma unroll
    for (int i = 0; i < 4; i++) {
      a[i] = *(const bf16x8*)(Al + (m0 + i * 16 + fr) * KP + kc + kg * 8);
      b[i] = *(const bf16x8*)(Bl + (n0 + i * 16 + fr) * KP + kc + kg * 8);
    }
#pragma unroll
    for (int i = 0; i < 4; i++)
#pragma unroll
      for (int j = 0; j < 4; j++)
        acc[i][j] = __builtin_amdgcn_mfma_f32_16x16x32_bf16(a[i], b[j], acc[i][j], 0, 0, 0);
  }
#pragma unroll
  for (int i = 0; i < 4; i++) {
    int row = m0b + m0 + i * 16 + (lane >> 4) * 4;
#pragma unroll
    for (int j = 0; j < 4; j++) {
      int col = n0b + n0 + j * 16 + (lane & 15);
#pragma unroll
      for (int r = 0; r < 4; r++)
        C[(size_t)(row + r) * N + col] = f2b(acc[i][j][r]);
    }
  }
}

// ---------------------------------------------------------------------------
// Stage-4 dense conv (K=64, 2 couts/cell, fp32): wave per node, lane = cell.
// ---------------------------------------------------------------------------
__global__ void __launch_bounds__(256) conv_k64_c2(
    const float* __restrict__ x, const float* __restrict__ W4 /*[64][64][2]*/,
    float* __restrict__ Y4, int c0, int CC) {
  int lane = threadIdx.x & 63;
  int n = blockIdx.x * 4 + (threadIdx.x >> 6);
  float xv = x[(size_t)n * 64 + lane];
  int cell = c0 + lane;
  const float2* wr = (const float2*)(W4 + (size_t)cell * 128);
  float a0 = 0.f, a1 = 0.f;
#pragma unroll
  for (int k = 0; k < 64; k++) {
    float xk = __shfl(xv, k, 64);
    float2 wk = wr[k];
    a0 = fmaf(xk, wk.x, a0);
    a1 = fmaf(xk, wk.y, a1);
  }
  if (lane < CC)
    *(float2*)(Y4 + (size_t)n * (CC * 2) + lane * 2) = make_float2(a0, a1);
}

// ---------------------------------------------------------------------------
// Stage 1, lane-parallel payload: ONE wave per node. Lanes 0..L-1 load
// pk/w4/x-row for L edges in ONE batched round (2 dependent rounds total),
// then a pure-VALU shuffle-broadcast loop does the conv math. Fluid then
// boundary; lin folded in. Writes by lane groups after full reductions.
// ---------------------------------------------------------------------------
__global__ void __launch_bounds__(256, 8) b1_stage1(
    const float* __restrict__ ff, const float* __restrict__ bfe,
    const float* __restrict__ fc0,
    const float* __restrict__ W0, const float* __restrict__ W1,
    const int* __restrict__ ftstart, const unsigned* __restrict__ fpk,
    const float4* __restrict__ fwt,
    const int* __restrict__ btstart, const unsigned* __restrict__ bpk,
    const float4* __restrict__ bwt,
    float* __restrict__ ans0, short* __restrict__ Xh96) {
  int lane = threadIdx.x & 63;
  int t = __builtin_amdgcn_readfirstlane(blockIdx.x * 4 + (threadIdx.x >> 6));
  int q = lane >> 4;
  int p = lane & 15;
  int cofs = (q & 1) + (q >> 1) * 8;

  float2 fa = make_float2(0.f, 0.f);
  {
    int s = __builtin_amdgcn_readfirstlane(ftstart[t]);
    int e1 = __builtin_amdgcn_readfirstlane(ftstart[t + 1]);
    for (int base = s; base < e1; base += 64) {
      int Ln = min(64, e1 - base);
      unsigned mypk = 0;
      float4 myw = make_float4(0.f, 0.f, 0.f, 0.f);
      float4 myx = make_float4(0.f, 0.f, 0.f, 0.f);
      if (lane < Ln) {
        mypk = fpk[base + lane];
        myw = fwt[base + lane];
        myx = *(const float4*)(ff + (size_t)(mypk & 16383) * 4);
      }
      for (int j = 0; j < Ln; j++) {
        unsigned pk = __shfl(mypk, j, 64);
        float wx = __shfl(myw.x, j, 64), wy = __shfl(myw.y, j, 64);
        float wz = __shfl(myw.z, j, 64), ww = __shfl(myw.w, j, 64);
        float xx = __shfl(myx.x, j, 64), xy = __shfl(myx.y, j, 64);
        float xz = __shfl(myx.z, j, 64), xw = __shfl(myx.w, j, 64);
        float wq = (q == 0) ? wx : (q == 1) ? wy : (q == 2) ? wz : ww;
        int cell = (int)(pk >> 14) + cofs;
        const float* Wc = W0 + cell * 128 + 2 * p;
        float2 k0 = *(const float2*)(Wc);
        float2 k1 = *(const float2*)(Wc + 32);
        float2 k2 = *(const float2*)(Wc + 64);
        float2 k3 = *(const float2*)(Wc + 96);
        fa.x = fmaf(wq, xx * k0.x + xy * k1.x + xz * k2.x + xw * k3.x, fa.x);
        fa.y = fmaf(wq, xx * k0.y + xy * k1.y + xz * k2.y + xw * k3.y, fa.y);
      }
    }
  }
  float2 ba = make_float2(0.f, 0.f);
  {
    int s = __builtin_amdgcn_readfirstlane(btstart[t]);
    int e1 = __builtin_amdgcn_readfirstlane(btstart[t + 1]);
    for (int base = s; base < e1; base += 64) {
      int Ln = min(64, e1 - base);
      unsigned mypk = 0;
      float4 myw = make_float4(0.f, 0.f, 0.f, 0.f);
      float4 myx = make_float4(0.f, 0.f, 0.f, 0.f);
      if (lane < Ln) {
        mypk = bpk[base + lane];
        myw = bwt[base + lane];
        myx = *(const float4*)(bfe + (size_t)(mypk & 16383) * 4);
      }
      for (int j = 0; j < Ln; j++) {
        unsigned pk = __shfl(mypk, j, 64);
        float wx = __shfl(myw.x, j, 64), wy = __shfl(myw.y, j, 64);
        float wz = __shfl(myw.z, j, 64), ww = __shfl(myw.w, j, 64);
        float xx = __shfl(myx.x, j, 64), xy = __shfl(myx.y, j, 64);
        float xz = __shfl(myx.z, j, 64), xw = __shfl(myx.w, j, 64);
        float wq = (q == 0) ? wx : (q == 1) ? wy : (q == 2) ? wz : ww;
        int cell = (int)(pk >> 14) + cofs;
        const float* Wc = W1 + cell * 128 + 2 * p;
        float2 k0 = *(const float2*)(Wc);
        float2 k1 = *(const float2*)(Wc + 32);
        float2 k2 = *(const float2*)(Wc + 64);
        float2 k3 = *(const float2*)(Wc + 96);
        ba.x = fmaf(wq, xx * k0.x + xy * k1.x + xz * k2.x + xw * k3.x, ba.x);
        ba.y = fmaf(wq, xx * k0.y + xy * k1.y + xz * k2.y + xw * k3.y, ba.y);
      }
    }
  }
  // full reductions: afterwards EVERY lane holds the total for its pair p
  fa.x += __shfl_xor(fa.x, 16, 64); fa.y += __shfl_xor(fa.y, 16, 64);
  fa.x += __shfl_xor(fa.x, 32, 64); fa.y += __shfl_xor(fa.y, 32, 64);
  ba.x += __shfl_xor(ba.x, 16, 64); ba.y += __shfl_xor(ba.y, 16, 64);
  ba.x += __shfl_xor(ba.x, 32, 64); ba.y += __shfl_xor(ba.y, 32, 64);
  if (lane < 16) {
    fa.x = fmaxf(fa.x, 0.f); fa.y = fmaxf(fa.y, 0.f);
    *(float2*)(ans0 + (size_t)t * 96 + 32 + 2 * p) = fa;
    *(unsigned*)(Xh96 + (size_t)t * 96 + 32 + 2 * p) = pack2(fa.x, fa.y);
  } else if (lane < 32) {
    ba.x = fmaxf(ba.x, 0.f); ba.y = fmaxf(ba.y, 0.f);
    *(float2*)(ans0 + (size_t)t * 96 + 64 + 2 * p) = ba;
    *(unsigned*)(Xh96 + (size_t)t * 96 + 64 + 2 * p) = pack2(ba.x, ba.y);
  } else if (lane < 48) {
    float4 fv = *(const float4*)(ff + (size_t)t * 4);
    float l0 = fv.x * fc0[2 * p] + fv.y * fc0[32 + 2 * p] +
               fv.z * fc0[64 + 2 * p] + fv.w * fc0[96 + 2 * p];
    float l1 = fv.x * fc0[2 * p + 1] + fv.y * fc0[32 + 2 * p + 1] +
               fv.z * fc0[64 + 2 * p + 1] + fv.w * fc0[96 + 2 * p + 1];
    l0 = fmaxf(l0, 0.f); l1 = fmaxf(l1, 0.f);
    *(float2*)(ans0 + (size_t)t * 96 + 2 * p) = make_float2(l0, l1);
    *(unsigned*)(Xh96 + (size_t)t * 96 + 2 * p) = pack2(l0, l1);
  }
}

// ---------------------------------------------------------------------------
// Phase B stages 2/3: lane-parallel payload preload (1 round per 64 edges),
// then 8-wide Y gathers whose addresses are all ready. One wave per target.
// ---------------------------------------------------------------------------
template <int CIN, int RESID, int WBF16>
__global__ void __launch_bounds__(256, 4) b23(
    const float* __restrict__ xin, const float* __restrict__ fc,
    const int* __restrict__ ftstart, const unsigned* __restrict__ epk,
    const float4* __restrict__ ewt, const short* __restrict__ Y,
    const float* __restrict__ resid, float* __restrict__ dest,
    short* __restrict__ Xh64, int c0, int CC, int init, int fin) {
  int lane = threadIdx.x & 63;
  int t = __builtin_amdgcn_readfirstlane(blockIdx.x * 4 + (threadIdx.x >> 6));
  int q = lane >> 4;
  int sub = lane & 15;
  int cofs = (q & 1) + (q >> 1) * 8;
  int YW = CC * 64;
  float a0 = 0.f, a1 = 0.f, a2 = 0.f, a3 = 0.f;
  if (init) {
    const float* xr = xin + (size_t)t * CIN;
#pragma unroll
    for (int kk = 0; kk < CIN / 4; kk++) {
      int k = q * (CIN / 4) + kk;
      float xv = xr[k];
      float4 fv = *(const float4*)(fc + (size_t)k * 64 + 4 * sub);
      a0 = fmaf(xv, fv.x, a0);
      a1 = fmaf(xv, fv.y, a1);
      a2 = fmaf(xv, fv.z, a2);
      a3 = fmaf(xv, fv.w, a3);
    }
  }
  int s = __builtin_amdgcn_readfirstlane(ftstart[t]);
  int e1 = __builtin_amdgcn_readfirstlane(ftstart[t + 1]);
  for (int base = s; base < e1; base += 64) {
    int Ln = min(64, e1 - base);
    unsigned mypk = 0;
    float4 myw = make_float4(0.f, 0.f, 0.f, 0.f);
    if (lane < Ln) {
      mypk = epk[base + lane];
      myw = ewt[base + lane];
    }
    int j = 0;
    for (; j + 7 < Ln; j += 8) {
      float wq_[8];
      uint2 r_[8];
#pragma unroll
      for (int u = 0; u < 8; u++) {
        unsigned pk = __shfl(mypk, j + u, 64);
        float wx = __shfl(myw.x, j + u, 64), wy = __shfl(myw.y, j + u, 64);
        float wz = __shfl(myw.z, j + u, 64), ww = __shfl(myw.w, j + u, 64);
        wq_[u] = (q == 0) ? wx : (q == 1) ? wy : (q == 2) ? wz : ww;
        int src = pk & 16383;
        int cell = (int)(pk >> 14) + cofs - c0;
        r_[u] = make_uint2(0, 0);
        if ((unsigned)cell < (unsigned)CC)
          r_[u] = *(const uint2*)(Y + (size_t)src * YW + cell * 64 + 4 * sub);
      }
#pragma unroll
      for (int u = 0; u < 8; u++) {
        a0 = fmaf(wq_[u], b2f_lo(r_[u].x), a0);
        a1 = fmaf(wq_[u], b2f_hi(r_[u].x), a1);
        a2 = fmaf(wq_[u], b2f_lo(r_[u].y), a2);
        a3 = fmaf(wq_[u], b2f_hi(r_[u].y), a3);
      }
    }
    for (; j < Ln; j++) {
      unsigned pk = __shfl(mypk, j, 64);
      float wx = __shfl(myw.x, j, 64), wy = __shfl(myw.y, j, 64);
      float wz = __shfl(myw.z, j, 64), ww = __shfl(myw.w, j, 64);
      float wq = (q == 0) ? wx : (q == 1) ? wy : (q == 2) ? wz : ww;
      int src = pk & 16383;
      int cell = (int)(pk >> 14) + cofs - c0;
      if ((unsigned)cell < (unsigned)CC) {
        uint2 r = *(const uint2*)(Y + (size_t)src * YW + cell * 64 + 4 * sub);
        a0 = fmaf(wq, b2f_lo(r.x), a0);
        a1 = fmaf(wq, b2f_hi(r.x), a1);
        a2 = fmaf(wq, b2f_lo(r.y), a2);
        a3 = fmaf(wq, b2f_hi(r.y), a3);
      }
    }
  }
  a0 += __shfl_xor(a0, 16, 64); a1 += __shfl_xor(a1, 16, 64);
  a2 += __shfl_xor(a2, 16, 64); a3 += __shfl_xor(a3, 16, 64);
  a0 += __shfl_xor(a0, 32, 64); a1 += __shfl_xor(a1, 32, 64);
  a2 += __shfl_xor(a2, 32, 64); a3 += __shfl_xor(a3, 32, 64);
  if (lane < 16) {
    float4* dst = (float4*)(dest + (size_t)t * 64 + 4 * sub);
    if (!init) {
      float4 d = *dst;
      a0 += d.x; a1 += d.y; a2 += d.z; a3 += d.w;
    }
    if (RESID && init) {
      float4 rd = *(const float4*)(resid + (size_t)t * 64 + 4 * sub);
      a0 += rd.x; a1 += rd.y; a2 += rd.z; a3 += rd.w;
    }
    if (fin) {
      a0 = fmaxf(a0, 0.f); a1 = fmaxf(a1, 0.f);
      a2 = fmaxf(a2, 0.f); a3 = fmaxf(a3, 0.f);
    }
    *dst = make_float4(a0, a1, a2, a3);
    if (WBF16 && fin) {
      uint2 pkd = make_uint2(pack2(a0, a1), pack2(a2, a3));
      *(uint2*)(Xh64 + (size_t)t * 64 + 4 * sub) = pkd;
    }
  }
}

// ---------------------------------------------------------------------------
// Phase B stage 4: out[t] = gather(Y4) + ans2@fc3 (lane-parallel slots).
// ---------------------------------------------------------------------------
__global__ void __launch_bounds__(256, 8) b4_stage4(
    const float* __restrict__ ans2, const float* __restrict__ fc3,
    const int* __restrict__ ftstart, const unsigned* __restrict__ epk,
    const float4* __restrict__ ewt, const float* __restrict__ Y4,
    float* __restrict__ partial, float* __restrict__ outp,
    int c0, int CC, int init, int fin) {
  int lane = threadIdx.x & 63;
  int t = blockIdx.x * 4 + (threadIdx.x >> 6);
  int s4 = ftstart[t] * 4, e4 = ftstart[t + 1] * 4;
  float m0 = 0.f, m1 = 0.f;
  for (int fq = s4 + lane; fq < e4; fq += 64) {
    int idx = fq >> 2, j = fq & 3;
    unsigned pk = epk[idx];
    float4 w4 = ewt[idx];
    int src = pk & 16383;
    int cell = (int)(pk >> 14) + (j & 1) + (j >> 1) * 8 - c0;
    float w = (j == 0) ? w4.x : (j == 1) ? w4.y : (j == 2) ? w4.z : w4.w;
    if ((unsigned)cell < (unsigned)CC) {
      float2 mm = *(const float2*)(Y4 + (size_t)src * (CC * 2) + cell * 2);
      m0 += w * mm.x;
      m1 += w * mm.y;
    }
  }
  if (init) {
    float a = ans2[(size_t)t * 64 + lane];
    m0 += a * fc3[lane * 2 + 0];
    m1 += a * fc3[lane * 2 + 1];
  }
#pragma unroll
  for (int off = 32; off > 0; off >>= 1) {
    m0 += __shfl_xor(m0, off, 64);
    m1 += __shfl_xor(m1, off, 64);
  }
  if (lane == 0) {
    if (!init) { m0 += partial[t * 2]; m1 += partial[t * 2 + 1]; }
    if (fin) { outp[t * 2] = m0; outp[t * 2 + 1] = m1; }
    else { partial[t * 2] = m0; partial[t * 2 + 1] = m1; }
  }
}

// ---------------------------------------------------------------------------
extern "C" void kernel_launch(void* const* d_in, const int* in_sizes, int n_in,
                              void* d_out, int out_size, void* d_ws, size_t ws_size,
                              hipStream_t stream) {
  const float* fp  = (const float*)d_in[0];
  const float* bp  = (const float*)d_in[1];
  const float* ff  = (const float*)d_in[2];
  const float* bfe = (const float*)d_in[3];
  const float* sup = (const float*)d_in[4];
  const int* fi  = (const int*)d_in[5];
  const int* fj  = (const int*)d_in[6];
  const int* bfi = (const int*)d_in[7];
  const int* bb  = (const int*)d_in[8];
  const float* W0 = (const float*)d_in[9];
  const float* W1 = (const float*)d_in[10];
  const float* W2 = (const float*)d_in[11];
  const float* W3 = (const float*)d_in[12];
  const float* W4 = (const float*)d_in[13];
  const float* fc0 = (const float*)d_in[14];
  const float* fc1 = (const float*)d_in[15];
  const float* fc2 = (const float*)d_in[16];
  const float* fc3 = (const float*)d_in[17];
  float* out = (float*)d_out;

  char* w = (char*)d_ws;
  size_t off = 0;
  auto alloc = [&](size_t bytes) {
    char* p = w + off;
    off += (bytes + 255) & ~size_t(255);
    return p;
  };
  float* ans0   = (float*)alloc((size_t)NF * 96 * 4);
  float* ans1   = (float*)alloc((size_t)NF * 64 * 4);
  float* ans2   = (float*)alloc((size_t)NF * 64 * 4);
  float* outpre = (float*)alloc((size_t)NF * 2 * 4);
  int* fthist  = (int*)alloc((size_t)NF * 4);
  int* bthist  = (int*)alloc((size_t)NF * 4);   // adjacent to fthist: one memset
  int* ftstart = (int*)alloc((size_t)(NF + 1) * 4);
  int* ftcur   = (int*)alloc((size_t)NF * 4);
  int* btstart = (int*)alloc((size_t)(NF + 1) * 4);
  int* btcur   = (int*)alloc((size_t)NF * 4);
  unsigned* fpk  = (unsigned*)alloc((size_t)EF * 4);
  float4* fwtP   = (float4*)alloc((size_t)EF * 16);
  unsigned* bpk  = (unsigned*)alloc((size_t)EB * 4);
  float4* bwtP   = (float4*)alloc((size_t)EB * 16);
  short* Xh96 = (short*)alloc((size_t)NF * 96 * 2);
  short* Xh64 = (short*)alloc((size_t)NF * 64 * 2);
  short* BT = (short*)alloc((size_t)4096 * 96 * 2);
  char* Yreg = w + off;
  size_t avail = (ws_size > off) ? (ws_size - off) : 0;
  size_t percell = (size_t)NF * 64 * 2;
  int CC = 64;
  while (CC > 8 && (size_t)CC * percell > avail) CC >>= 1;
  int S = 64 / CC;
  short* Y  = (short*)Yreg;
  float* Y4 = (float*)Yreg;

  hipMemsetAsync(fthist, 0, (size_t)NF * 8, stream);

  dual_hist<<<FBLK + BBLK, 256, 0, stream>>>(fi, bfi, fthist, bthist);
  csr_scan2<<<2, 1024, 0, stream>>>(fthist, bthist, ftstart, ftcur, btstart, btcur);
  dual_scatter_payload<<<FBLK + BBLK, 256, 0, stream>>>(fi, fj, bfi, bb, fp, bp, sup,
                                                        ftcur, btcur, fpk, fwtP, bpk, bwtP);

  // Stage 1: lane-parallel fused, 1 wave/node. Emits ans0 + bf16 Xh96.
  b1_stage1<<<NF / 4, 256, 0, stream>>>(ff, bfe, fc0, W0, W1,
                                        ftstart, fpk, fwtP, btstart, bpk, bwtP,
                                        ans0, Xh96);
  // Stage 2: MFMA GEMM + gather. Emits ans1 + bf16 Xh64.
  buildBT<<<(4096 * 96 + 255) / 256, 256, 0, stream>>>(W2, BT, 96);
  for (int c = 0; c < S; c++) {
    int c0 = c * CC;
    gemm_bf16<96><<<dim3(NF / 128, CC * 64 / 128), 256, 0, stream>>>(
        Xh96, BT + (size_t)c0 * 64 * 96, Y, CC * 64);
    b23<96, 0, 1><<<NF / 4, 256, 0, stream>>>(ans0, fc1, ftstart, fpk, fwtP,
                                              Y, nullptr, ans1, Xh64,
                                              c0, CC, c == 0, c == S - 1);
  }
  // Stage 3
  buildBT<<<(4096 * 64 + 255) / 256, 256, 0, stream>>>(W3, BT, 64);
  for (int c = 0; c < S; c++) {
    int c0 = c * CC;
    gemm_bf16<64><<<dim3(NF / 128, CC * 64 / 128), 256, 0, stream>>>(
        Xh64, BT + (size_t)c0 * 64 * 64, Y, CC * 64);
    b23<64, 1, 0><<<NF / 4, 256, 0, stream>>>(ans1, fc2, ftstart, fpk, fwtP,
                                              Y, ans1, ans2, nullptr,
                                              c0, CC, c == 0, c == S - 1);
  }
  // Stage 4
  for (int c = 0; c < S; c++) {
    int c0 = c * CC;
    conv_k64_c2<<<NF / 4, 256, 0, stream>>>(ans2, W4, Y4, c0, CC);
    b4_stage4<<<NF / 4, 256, 0, stream>>>(ans2, fc3, ftstart, fpk, fwtP,
                                          Y4, outpre, out, c0, CC, c == 0, c == S - 1);
  }
}

// Round 13
// 318.727 us; speedup vs baseline: 1.4121x; 1.1698x over previous
//
#include <hip/hip_runtime.h>

#define NF 16384
#define NB 4096
#define EF 262144
#define EB 65536
#define FBLK 1024   // EF/256
#define BBLK 256    // EB/256

typedef __attribute__((ext_vector_type(8))) short bf16x8;
typedef __attribute__((ext_vector_type(4))) float f32x4;

__device__ __forceinline__ short f2b(float f) {
  unsigned u = __float_as_uint(f);
  u += 0x7fff + ((u >> 16) & 1);   // RNE
  return (short)(u >> 16);
}
__device__ __forceinline__ unsigned pack2(float lo, float hi) {
  return (unsigned)(unsigned short)f2b(lo) | ((unsigned)(unsigned short)f2b(hi) << 16);
}
__device__ __forceinline__ float b2f_lo(unsigned u) {
  return __uint_as_float(u << 16);
}
__device__ __forceinline__ float b2f_hi(unsigned u) {
  return __uint_as_float(u & 0xffff0000u);
}

// ---------------------------------------------------------------------------
// Target CSR: histogram (merged fluid+boundary).
// ---------------------------------------------------------------------------
__global__ void __launch_bounds__(256) dual_hist(const int* __restrict__ fi,
                                                 const int* __restrict__ bfi,
                                                 int* __restrict__ fhist,
                                                 int* __restrict__ bhist) {
  int bid = blockIdx.x;
  if (bid < FBLK) {
    int e = bid * 256 + threadIdx.x;
    atomicAdd(fhist + fi[e], 1);
  } else {
    int e = (bid - FBLK) * 256 + threadIdx.x;
    atomicAdd(bhist + bfi[e], 1);
  }
}

__global__ void __launch_bounds__(1024) csr_scan2(const int* __restrict__ fhist,
                                                  const int* __restrict__ bhist,
                                                  int* __restrict__ fstart, int* __restrict__ fcur,
                                                  int* __restrict__ bstart, int* __restrict__ bcur) {
  const int* hist = blockIdx.x ? bhist : fhist;
  int* start = blockIdx.x ? bstart : fstart;
  int* cursor = blockIdx.x ? bcur : fcur;
  __shared__ int wtot[16];
  int t = threadIdx.x;
  int lane = t & 63, wv = t >> 6;
  int base = t * 16;
  int vals[16];
  int s = 0;
#pragma unroll
  for (int k = 0; k < 16; k++) { vals[k] = hist[base + k]; s += vals[k]; }
  int ss = s;
  for (int off = 1; off < 64; off <<= 1) {
    int o = __shfl_up(ss, off, 64);
    if (lane >= off) ss += o;
  }
  if (lane == 63) wtot[wv] = ss;
  __syncthreads();
  if (t < 16) {
    int v = wtot[t];
    int vv = v;
    for (int off = 1; off < 16; off <<= 1) {
      int o = __shfl_up(vv, off, 64);
      if (t >= off) vv += o;
    }
    wtot[t] = vv - v;
  }
  __syncthreads();
  int run = ss - s + wtot[wv];
#pragma unroll
  for (int k = 0; k < 16; k++) { start[base + k] = run; cursor[base + k] = run; run += vals[k]; }
  if (t == 1023) start[16384] = run;
}

// ---------------------------------------------------------------------------
// Merged scatter + payload + tent-basis.
// ---------------------------------------------------------------------------
__global__ void __launch_bounds__(256) dual_scatter_payload(
    const int* __restrict__ fi, const int* __restrict__ fj,
    const int* __restrict__ bfi, const int* __restrict__ bb,
    const float* __restrict__ fp, const float* __restrict__ bp,
    const float* __restrict__ supportp,
    int* __restrict__ fcur, int* __restrict__ bcur,
    unsigned* __restrict__ fpk, float4* __restrict__ fwt,
    unsigned* __restrict__ bpk, float4* __restrict__ bwt) {
  int bid = blockIdx.x;
  bool fluid = bid < FBLK;
  int e = (fluid ? bid : bid - FBLK) * 256 + threadIdx.x;
  int ti = fluid ? fi[e] : bfi[e];
  int si = fluid ? fj[e] : bb[e];
  const float2* pT2 = (const float2*)fp;
  const float2* pS2 = fluid ? (const float2*)fp : (const float2*)bp;
  float sign = fluid ? -1.f : 1.f;
  float inv_sup = 1.0f / supportp[0];
  float2 pt = pT2[ti];
  float2 ps = pS2[si];
  // d = sign*(src-tgt)/support. (-1)*(+0) = -0 preserves reference signed
  // zeros for self-edges (atan2(-0,-0) = -pi).
  float dx = sign * ((ps.x - pt.x) * inv_sup);
  float dy = sign * ((ps.y - pt.y) * inv_sup);
  dx = fminf(fmaxf(dx, -1.f), 1.f);
  dy = fminf(fmaxf(dy, -1.f), 1.f);
  float r = sqrtf(dx * dx + dy * dy + 1e-12f);
  float theta;
  if (dx == 0.0f && dy == 0.0f) {
    float mag = __builtin_signbitf(dx) ? 3.14159265358979323846f : 0.0f;
    theta = __builtin_signbitf(dy) ? -mag : mag;
  } else {
    theta = atan2f(dy, dx);
  }
  float u = 2.f * r - 1.f;
  float v = theta * (1.f / 3.14159265358979323846f);
  float tu = (u + 1.f) * 3.5f;
  float tv = (v + 1.f) * 3.5f;
  int iu = min(max((int)floorf(tu), 0), 6);
  int iv = min(max((int)floorf(tv), 0), 6);
  float wu0 = fmaxf(0.f, 1.f - fabsf(tu - (float)iu));
  float wu1 = fmaxf(0.f, 1.f - fabsf(tu - (float)(iu + 1)));
  float wv0 = fmaxf(0.f, 1.f - fabsf(tv - (float)iv));
  float wv1 = fmaxf(0.f, 1.f - fabsf(tv - (float)(iv + 1)));
  unsigned pk = (unsigned)si | ((unsigned)(iu * 8 + iv) << 14);
  float4 w4 = make_float4(wu0 * wv0, wu0 * wv1, wu1 * wv0, wu1 * wv1);
  if (fluid) {
    int p = atomicAdd(fcur + ti, 1);
    fpk[p] = pk; fwt[p] = w4;
  } else {
    int p = atomicAdd(bcur + ti, 1);
    bpk[p] = pk; bwt[p] = w4;
  }
}

__global__ void __launch_bounds__(256) buildBT(const float* __restrict__ W,
                                               short* __restrict__ BT, int K) {
  int tid = blockIdx.x * 256 + threadIdx.x;
  if (tid >= 4096 * K) return;
  int k = tid % K, n = tid / K;
  BT[tid] = f2b(W[((size_t)(n >> 6) * K + k) * 64 + (n & 63)]);
}

// BT4[n][k] = bf16(W4[cell=n>>1][k][q=n&1]); n in [0,128), k in [0,64)
__global__ void __launch_bounds__(256) buildBT4(const float* __restrict__ W4,
                                                short* __restrict__ BT4) {
  int tid = blockIdx.x * 256 + threadIdx.x;
  if (tid >= 128 * 64) return;
  int k = tid & 63, n = tid >> 6;
  BT4[tid] = f2b(W4[((size_t)(n >> 1) * 64 + k) * 2 + (n & 1)]);
}

// ---------------------------------------------------------------------------
// Dense MFMA GEMM, LDS-staged tiles (conflict-free padded rows, 16B aligned).
// ---------------------------------------------------------------------------
template <int K>
__global__ void __launch_bounds__(256, 2) gemm_bf16(
    const short* __restrict__ A, const short* __restrict__ BT,
    short* __restrict__ C, int N) {
  constexpr int KP = K + 8;  // padded row (shorts): 16B-aligned, 2-way-bank only
  __shared__ __align__(16) short Al[128 * KP];
  __shared__ __align__(16) short Bl[128 * KP];
  int tid = threadIdx.x;
  int lane = tid & 63;
  int w = tid >> 6;
  int m0b = blockIdx.x * 128;
  int n0b = blockIdx.y * 128;
  constexpr int ROWV = K / 8;  // float4s per row
  for (int f = tid; f < 128 * ROWV; f += 256) {
    int r = f / ROWV, c = f % ROWV;
    *(float4*)(Al + r * KP + c * 8) = *(const float4*)(A + (size_t)(m0b + r) * K + c * 8);
    *(float4*)(Bl + r * KP + c * 8) = *(const float4*)(BT + (size_t)(n0b + r) * K + c * 8);
  }
  __syncthreads();
  int m0 = (w & 1) * 64;
  int n0 = (w >> 1) * 64;
  int fr = lane & 15;
  int kg = lane >> 4;
  f32x4 acc[4][4] = {};
#pragma unroll
  for (int kc = 0; kc < K; kc += 32) {
    bf16x8 a[4], b[4];
#pragma unroll
    for (int i = 0; i < 4; i++) {
      a[i] = *(const bf16x8*)(Al + (m0 + i * 16 + fr) * KP + kc + kg * 8);
      b[i] = *(const bf16x8*)(Bl + (n0 + i * 16 + fr) * KP + kc + kg * 8);
    }
#pragma unroll
    for (int i = 0; i < 4; i++)
#pragma unroll
      for (int j = 0; j < 4; j++)
        acc[i][j] = __builtin_amdgcn_mfma_f32_16x16x32_bf16(a[i], b[j], acc[i][j], 0, 0, 0);
  }
#pragma unroll
  for (int i = 0; i < 4; i++) {
    int row = m0b + m0 + i * 16 + (lane >> 4) * 4;
#pragma unroll
    for (int j = 0; j < 4; j++) {
      int col = n0b + n0 + j * 16 + (lane & 15);
#pragma unroll
      for (int r = 0; r < 4; r++)
        C[(size_t)(row + r) * N + col] = f2b(acc[i][j][r]);
    }
  }
}

// ---------------------------------------------------------------------------
// Stage 1, lane-parallel payload: ONE wave per node. Lanes 0..L-1 load
// pk/w4/x-row for L edges in ONE batched round (2 dependent rounds total),
// then a pure-VALU shuffle-broadcast loop does the conv math.
// ---------------------------------------------------------------------------
__global__ void __launch_bounds__(256, 8) b1_stage1(
    const float* __restrict__ ff, const float* __restrict__ bfe,
    const float* __restrict__ fc0,
    const float* __restrict__ W0, const float* __restrict__ W1,
    const int* __restrict__ ftstart, const unsigned* __restrict__ fpk,
    const float4* __restrict__ fwt,
    const int* __restrict__ btstart, const unsigned* __restrict__ bpk,
    const float4* __restrict__ bwt,
    float* __restrict__ ans0, short* __restrict__ Xh96) {
  int lane = threadIdx.x & 63;
  int t = __builtin_amdgcn_readfirstlane(blockIdx.x * 4 + (threadIdx.x >> 6));
  int q = lane >> 4;
  int p = lane & 15;
  int cofs = (q & 1) + (q >> 1) * 8;

  float2 fa = make_float2(0.f, 0.f);
  {
    int s = __builtin_amdgcn_readfirstlane(ftstart[t]);
    int e1 = __builtin_amdgcn_readfirstlane(ftstart[t + 1]);
    for (int base = s; base < e1; base += 64) {
      int Ln = min(64, e1 - base);
      unsigned mypk = 0;
      float4 myw = make_float4(0.f, 0.f, 0.f, 0.f);
      float4 myx = make_float4(0.f, 0.f, 0.f, 0.f);
      if (lane < Ln) {
        mypk = fpk[base + lane];
        myw = fwt[base + lane];
        myx = *(const float4*)(ff + (size_t)(mypk & 16383) * 4);
      }
      for (int j = 0; j < Ln; j++) {
        unsigned pk = __shfl(mypk, j, 64);
        float wx = __shfl(myw.x, j, 64), wy = __shfl(myw.y, j, 64);
        float wz = __shfl(myw.z, j, 64), ww = __shfl(myw.w, j, 64);
        float xx = __shfl(myx.x, j, 64), xy = __shfl(myx.y, j, 64);
        float xz = __shfl(myx.z, j, 64), xw = __shfl(myx.w, j, 64);
        float wq = (q == 0) ? wx : (q == 1) ? wy : (q == 2) ? wz : ww;
        int cell = (int)(pk >> 14) + cofs;
        const float* Wc = W0 + cell * 128 + 2 * p;
        float2 k0 = *(const float2*)(Wc);
        float2 k1 = *(const float2*)(Wc + 32);
        float2 k2 = *(const float2*)(Wc + 64);
        float2 k3 = *(const float2*)(Wc + 96);
        fa.x = fmaf(wq, xx * k0.x + xy * k1.x + xz * k2.x + xw * k3.x, fa.x);
        fa.y = fmaf(wq, xx * k0.y + xy * k1.y + xz * k2.y + xw * k3.y, fa.y);
      }
    }
  }
  float2 ba = make_float2(0.f, 0.f);
  {
    int s = __builtin_amdgcn_readfirstlane(btstart[t]);
    int e1 = __builtin_amdgcn_readfirstlane(btstart[t + 1]);
    for (int base = s; base < e1; base += 64) {
      int Ln = min(64, e1 - base);
      unsigned mypk = 0;
      float4 myw = make_float4(0.f, 0.f, 0.f, 0.f);
      float4 myx = make_float4(0.f, 0.f, 0.f, 0.f);
      if (lane < Ln) {
        mypk = bpk[base + lane];
        myw = bwt[base + lane];
        myx = *(const float4*)(bfe + (size_t)(mypk & 16383) * 4);
      }
      for (int j = 0; j < Ln; j++) {
        unsigned pk = __shfl(mypk, j, 64);
        float wx = __shfl(myw.x, j, 64), wy = __shfl(myw.y, j, 64);
        float wz = __shfl(myw.z, j, 64), ww = __shfl(myw.w, j, 64);
        float xx = __shfl(myx.x, j, 64), xy = __shfl(myx.y, j, 64);
        float xz = __shfl(myx.z, j, 64), xw = __shfl(myx.w, j, 64);
        float wq = (q == 0) ? wx : (q == 1) ? wy : (q == 2) ? wz : ww;
        int cell = (int)(pk >> 14) + cofs;
        const float* Wc = W1 + cell * 128 + 2 * p;
        float2 k0 = *(const float2*)(Wc);
        float2 k1 = *(const float2*)(Wc + 32);
        float2 k2 = *(const float2*)(Wc + 64);
        float2 k3 = *(const float2*)(Wc + 96);
        ba.x = fmaf(wq, xx * k0.x + xy * k1.x + xz * k2.x + xw * k3.x, ba.x);
        ba.y = fmaf(wq, xx * k0.y + xy * k1.y + xz * k2.y + xw * k3.y, ba.y);
      }
    }
  }
  fa.x += __shfl_xor(fa.x, 16, 64); fa.y += __shfl_xor(fa.y, 16, 64);
  fa.x += __shfl_xor(fa.x, 32, 64); fa.y += __shfl_xor(fa.y, 32, 64);
  ba.x += __shfl_xor(ba.x, 16, 64); ba.y += __shfl_xor(ba.y, 16, 64);
  ba.x += __shfl_xor(ba.x, 32, 64); ba.y += __shfl_xor(ba.y, 32, 64);
  if (lane < 16) {
    fa.x = fmaxf(fa.x, 0.f); fa.y = fmaxf(fa.y, 0.f);
    *(float2*)(ans0 + (size_t)t * 96 + 32 + 2 * p) = fa;
    *(unsigned*)(Xh96 + (size_t)t * 96 + 32 + 2 * p) = pack2(fa.x, fa.y);
  } else if (lane < 32) {
    ba.x = fmaxf(ba.x, 0.f); ba.y = fmaxf(ba.y, 0.f);
    *(float2*)(ans0 + (size_t)t * 96 + 64 + 2 * p) = ba;
    *(unsigned*)(Xh96 + (size_t)t * 96 + 64 + 2 * p) = pack2(ba.x, ba.y);
  } else if (lane < 48) {
    float4 fv = *(const float4*)(ff + (size_t)t * 4);
    float l0 = fv.x * fc0[2 * p] + fv.y * fc0[32 + 2 * p] +
               fv.z * fc0[64 + 2 * p] + fv.w * fc0[96 + 2 * p];
    float l1 = fv.x * fc0[2 * p + 1] + fv.y * fc0[32 + 2 * p + 1] +
               fv.z * fc0[64 + 2 * p + 1] + fv.w * fc0[96 + 2 * p + 1];
    l0 = fmaxf(l0, 0.f); l1 = fmaxf(l1, 0.f);
    *(float2*)(ans0 + (size_t)t * 96 + 2 * p) = make_float2(l0, l1);
    *(unsigned*)(Xh96 + (size_t)t * 96 + 2 * p) = pack2(l0, l1);
  }
}

// ---------------------------------------------------------------------------
// Phase B stages 2/3: lane-parallel payload preload, 8-wide Y gathers.
// ---------------------------------------------------------------------------
template <int CIN, int RESID, int WBF16>
__global__ void __launch_bounds__(256, 4) b23(
    const float* __restrict__ xin, const float* __restrict__ fc,
    const int* __restrict__ ftstart, const unsigned* __restrict__ epk,
    const float4* __restrict__ ewt, const short* __restrict__ Y,
    const float* __restrict__ resid, float* __restrict__ dest,
    short* __restrict__ Xh64, int c0, int CC, int init, int fin) {
  int lane = threadIdx.x & 63;
  int t = __builtin_amdgcn_readfirstlane(blockIdx.x * 4 + (threadIdx.x >> 6));
  int q = lane >> 4;
  int sub = lane & 15;
  int cofs = (q & 1) + (q >> 1) * 8;
  int YW = CC * 64;
  float a0 = 0.f, a1 = 0.f, a2 = 0.f, a3 = 0.f;
  if (init) {
    const float* xr = xin + (size_t)t * CIN;
#pragma unroll
    for (int kk = 0; kk < CIN / 4; kk++) {
      int k = q * (CIN / 4) + kk;
      float xv = xr[k];
      float4 fv = *(const float4*)(fc + (size_t)k * 64 + 4 * sub);
      a0 = fmaf(xv, fv.x, a0);
      a1 = fmaf(xv, fv.y, a1);
      a2 = fmaf(xv, fv.z, a2);
      a3 = fmaf(xv, fv.w, a3);
    }
  }
  int s = __builtin_amdgcn_readfirstlane(ftstart[t]);
  int e1 = __builtin_amdgcn_readfirstlane(ftstart[t + 1]);
  for (int base = s; base < e1; base += 64) {
    int Ln = min(64, e1 - base);
    unsigned mypk = 0;
    float4 myw = make_float4(0.f, 0.f, 0.f, 0.f);
    if (lane < Ln) {
      mypk = epk[base + lane];
      myw = ewt[base + lane];
    }
    int j = 0;
    for (; j + 7 < Ln; j += 8) {
      float wq_[8];
      uint2 r_[8];
#pragma unroll
      for (int u = 0; u < 8; u++) {
        unsigned pk = __shfl(mypk, j + u, 64);
        float wx = __shfl(myw.x, j + u, 64), wy = __shfl(myw.y, j + u, 64);
        float wz = __shfl(myw.z, j + u, 64), ww = __shfl(myw.w, j + u, 64);
        wq_[u] = (q == 0) ? wx : (q == 1) ? wy : (q == 2) ? wz : ww;
        int src = pk & 16383;
        int cell = (int)(pk >> 14) + cofs - c0;
        r_[u] = make_uint2(0, 0);
        if ((unsigned)cell < (unsigned)CC)
          r_[u] = *(const uint2*)(Y + (size_t)src * YW + cell * 64 + 4 * sub);
      }
#pragma unroll
      for (int u = 0; u < 8; u++) {
        a0 = fmaf(wq_[u], b2f_lo(r_[u].x), a0);
        a1 = fmaf(wq_[u], b2f_hi(r_[u].x), a1);
        a2 = fmaf(wq_[u], b2f_lo(r_[u].y), a2);
        a3 = fmaf(wq_[u], b2f_hi(r_[u].y), a3);
      }
    }
    for (; j < Ln; j++) {
      unsigned pk = __shfl(mypk, j, 64);
      float wx = __shfl(myw.x, j, 64), wy = __shfl(myw.y, j, 64);
      float wz = __shfl(myw.z, j, 64), ww = __shfl(myw.w, j, 64);
      float wq = (q == 0) ? wx : (q == 1) ? wy : (q == 2) ? wz : ww;
      int src = pk & 16383;
      int cell = (int)(pk >> 14) + cofs - c0;
      if ((unsigned)cell < (unsigned)CC) {
        uint2 r = *(const uint2*)(Y + (size_t)src * YW + cell * 64 + 4 * sub);
        a0 = fmaf(wq, b2f_lo(r.x), a0);
        a1 = fmaf(wq, b2f_hi(r.x), a1);
        a2 = fmaf(wq, b2f_lo(r.y), a2);
        a3 = fmaf(wq, b2f_hi(r.y), a3);
      }
    }
  }
  a0 += __shfl_xor(a0, 16, 64); a1 += __shfl_xor(a1, 16, 64);
  a2 += __shfl_xor(a2, 16, 64); a3 += __shfl_xor(a3, 16, 64);
  a0 += __shfl_xor(a0, 32, 64); a1 += __shfl_xor(a1, 32, 64);
  a2 += __shfl_xor(a2, 32, 64); a3 += __shfl_xor(a3, 32, 64);
  if (lane < 16) {
    float4* dst = (float4*)(dest + (size_t)t * 64 + 4 * sub);
    if (!init) {
      float4 d = *dst;
      a0 += d.x; a1 += d.y; a2 += d.z; a3 += d.w;
    }
    if (RESID && init) {
      float4 rd = *(const float4*)(resid + (size_t)t * 64 + 4 * sub);
      a0 += rd.x; a1 += rd.y; a2 += rd.z; a3 += rd.w;
    }
    if (fin) {
      a0 = fmaxf(a0, 0.f); a1 = fmaxf(a1, 0.f);
      a2 = fmaxf(a2, 0.f); a3 = fmaxf(a3, 0.f);
    }
    *dst = make_float4(a0, a1, a2, a3);
    if (WBF16 && fin) {
      uint2 pkd = make_uint2(pack2(a0, a1), pack2(a2, a3));
      *(uint2*)(Xh64 + (size_t)t * 64 + 4 * sub) = pkd;
    }
  }
}

// ---------------------------------------------------------------------------
// Phase B stage 4: out[t] = gather(bf16 Y4h[NF][128]) + ans2@fc3. Single pass.
// ---------------------------------------------------------------------------
__global__ void __launch_bounds__(256, 8) b4_stage4(
    const float* __restrict__ ans2, const float* __restrict__ fc3,
    const int* __restrict__ ftstart, const unsigned* __restrict__ epk,
    const float4* __restrict__ ewt, const short* __restrict__ Y4h,
    float* __restrict__ outp) {
  int lane = threadIdx.x & 63;
  int t = blockIdx.x * 4 + (threadIdx.x >> 6);
  int s4 = ftstart[t] * 4, e4 = ftstart[t + 1] * 4;
  float m0 = 0.f, m1 = 0.f;
  for (int fq = s4 + lane; fq < e4; fq += 64) {
    int idx = fq >> 2, j = fq & 3;
    unsigned pk = epk[idx];
    float4 w4 = ewt[idx];
    int src = pk & 16383;
    int cell = (int)(pk >> 14) + (j & 1) + (j >> 1) * 8;
    float w = (j == 0) ? w4.x : (j == 1) ? w4.y : (j == 2) ? w4.z : w4.w;
    unsigned mm = *(const unsigned*)(Y4h + (size_t)src * 128 + cell * 2);
    m0 = fmaf(w, b2f_lo(mm), m0);
    m1 = fmaf(w, b2f_hi(mm), m1);
  }
  {
    float a = ans2[(size_t)t * 64 + lane];
    m0 += a * fc3[lane * 2 + 0];
    m1 += a * fc3[lane * 2 + 1];
  }
#pragma unroll
  for (int off = 32; off > 0; off >>= 1) {
    m0 += __shfl_xor(m0, off, 64);
    m1 += __shfl_xor(m1, off, 64);
  }
  if (lane == 0) {
    outp[t * 2] = m0;
    outp[t * 2 + 1] = m1;
  }
}

// ---------------------------------------------------------------------------
extern "C" void kernel_launch(void* const* d_in, const int* in_sizes, int n_in,
                              void* d_out, int out_size, void* d_ws, size_t ws_size,
                              hipStream_t stream) {
  const float* fp  = (const float*)d_in[0];
  const float* bp  = (const float*)d_in[1];
  const float* ff  = (const float*)d_in[2];
  const float* bfe = (const float*)d_in[3];
  const float* sup = (const float*)d_in[4];
  const int* fi  = (const int*)d_in[5];
  const int* fj  = (const int*)d_in[6];
  const int* bfi = (const int*)d_in[7];
  const int* bb  = (const int*)d_in[8];
  const float* W0 = (const float*)d_in[9];
  const float* W1 = (const float*)d_in[10];
  const float* W2 = (const float*)d_in[11];
  const float* W3 = (const float*)d_in[12];
  const float* W4 = (const float*)d_in[13];
  const float* fc0 = (const float*)d_in[14];
  const float* fc1 = (const float*)d_in[15];
  const float* fc2 = (const float*)d_in[16];
  const float* fc3 = (const float*)d_in[17];
  float* out = (float*)d_out;

  char* w = (char*)d_ws;
  size_t off = 0;
  auto alloc = [&](size_t bytes) {
    char* p = w + off;
    off += (bytes + 255) & ~size_t(255);
    return p;
  };
  float* ans0   = (float*)alloc((size_t)NF * 96 * 4);
  float* ans1   = (float*)alloc((size_t)NF * 64 * 4);
  float* ans2   = (float*)alloc((size_t)NF * 64 * 4);
  int* fthist  = (int*)alloc((size_t)NF * 4);
  int* bthist  = (int*)alloc((size_t)NF * 4);   // adjacent to fthist: one memset
  int* ftstart = (int*)alloc((size_t)(NF + 1) * 4);
  int* ftcur   = (int*)alloc((size_t)NF * 4);
  int* btstart = (int*)alloc((size_t)(NF + 1) * 4);
  int* btcur   = (int*)alloc((size_t)NF * 4);
  unsigned* fpk  = (unsigned*)alloc((size_t)EF * 4);
  float4* fwtP   = (float4*)alloc((size_t)EF * 16);
  unsigned* bpk  = (unsigned*)alloc((size_t)EB * 4);
  float4* bwtP   = (float4*)alloc((size_t)EB * 16);
  short* Xh96  = (short*)alloc((size_t)NF * 96 * 2);
  short* Xh64  = (short*)alloc((size_t)NF * 64 * 2);   // bf16 ans1
  short* Xh64b = (short*)alloc((size_t)NF * 64 * 2);   // bf16 ans2
  short* BT = (short*)alloc((size_t)4096 * 96 * 2);
  short* BT4 = (short*)alloc((size_t)128 * 64 * 2);
  char* Yreg = w + off;
  size_t avail = (ws_size > off) ? (ws_size - off) : 0;
  size_t percell = (size_t)NF * 64 * 2;
  int CC = 64;
  while (CC > 8 && (size_t)CC * percell > avail) CC >>= 1;
  int S = 64 / CC;
  short* Y   = (short*)Yreg;
  short* Y4h = (short*)Yreg;  // [NF][128] bf16, 4MB (reuses Y region)

  hipMemsetAsync(fthist, 0, (size_t)NF * 8, stream);

  dual_hist<<<FBLK + BBLK, 256, 0, stream>>>(fi, bfi, fthist, bthist);
  csr_scan2<<<2, 1024, 0, stream>>>(fthist, bthist, ftstart, ftcur, btstart, btcur);
  dual_scatter_payload<<<FBLK + BBLK, 256, 0, stream>>>(fi, fj, bfi, bb, fp, bp, sup,
                                                        ftcur, btcur, fpk, fwtP, bpk, bwtP);

  // Stage 1: lane-parallel fused, 1 wave/node. Emits ans0 + bf16 Xh96.
  b1_stage1<<<NF / 4, 256, 0, stream>>>(ff, bfe, fc0, W0, W1,
                                        ftstart, fpk, fwtP, btstart, bpk, bwtP,
                                        ans0, Xh96);
  // Stage 2: MFMA GEMM + gather. Emits ans1 + bf16 Xh64.
  buildBT<<<(4096 * 96 + 255) / 256, 256, 0, stream>>>(W2, BT, 96);
  for (int c = 0; c < S; c++) {
    int c0 = c * CC;
    gemm_bf16<96><<<dim3(NF / 128, CC * 64 / 128), 256, 0, stream>>>(
        Xh96, BT + (size_t)c0 * 64 * 96, Y, CC * 64);
    b23<96, 0, 1><<<NF / 4, 256, 0, stream>>>(ans0, fc1, ftstart, fpk, fwtP,
                                              Y, nullptr, ans1, Xh64,
                                              c0, CC, c == 0, c == S - 1);
  }
  // Stage 3: emits ans2 + bf16 Xh64b.
  buildBT<<<(4096 * 64 + 255) / 256, 256, 0, stream>>>(W3, BT, 64);
  for (int c = 0; c < S; c++) {
    int c0 = c * CC;
    gemm_bf16<64><<<dim3(NF / 128, CC * 64 / 128), 256, 0, stream>>>(
        Xh64, BT + (size_t)c0 * 64 * 64, Y, CC * 64);
    b23<64, 1, 1><<<NF / 4, 256, 0, stream>>>(ans1, fc2, ftstart, fpk, fwtP,
                                              Y, ans1, ans2, Xh64b,
                                              c0, CC, c == 0, c == S - 1);
  }
  // Stage 4: W4 conv as a single MFMA GEMM [NF x 64] @ [64 x 128], then gather.
  buildBT4<<<32, 256, 0, stream>>>(W4, BT4);
  gemm_bf16<64><<<dim3(NF / 128, 1), 256, 0, stream>>>(Xh64b, BT4, Y4h, 128);
  b4_stage4<<<NF / 4, 256, 0, stream>>>(ans2, fc3, ftstart, fpk, fwtP, Y4h, out);
}